// Round 12
// baseline (874.076 us; speedup 1.0000x reference)
//
#include <hip/hip_runtime.h>
#include <math.h>

// Problem constants (match reference)
#define B_      4
#define L_      1024
#define D_INNC  8      // D_IN
#define DMODEL  512
#define DEPTH_  4
#define DINNER  1024
#define DSTATE  16
#define DCONV   4
#define DTRANK  32
#define MTOT    (B_*L_)   // 4096
#define CHUNKS  64
#define CLEN    16        // L_/CHUNKS
#define XPSPLIT 8         // xp GEMM K-splits (K=1024 -> 8 x 128)

typedef float f32x4 __attribute__((ext_vector_type(4)));
typedef short s16x8 __attribute__((ext_vector_type(8)));
typedef unsigned short u16;
typedef unsigned short u16x4v __attribute__((ext_vector_type(4)));

#define GLOBAL_AS __attribute__((address_space(1)))
#define LDS_AS    __attribute__((address_space(3)))

// fp32 -> bf16 round-to-nearest-even
__device__ __forceinline__ u16 f2bf(float v) {
    unsigned b = __float_as_uint(v);
    return (u16)((b + 0x7FFF + ((b >> 16) & 1)) >> 16);
}
__device__ __forceinline__ float bf2f(u16 h) {
    return __uint_as_float((unsigned)h << 16);
}

// ---------------------------------------------------------------------------
// h = x @ in_w^T + in_b  -> bf16 (4096 x 512, K=8)
__global__ __launch_bounds__(256) void in_proj_kernel(
    const float* __restrict__ x, const float* __restrict__ w,
    const float* __restrict__ bias, u16* __restrict__ hb)
{
    int idx = blockIdx.x * 256 + threadIdx.x;
    int m = idx / DMODEL, d = idx % DMODEL;
    const float* xr = x + m * D_INNC;
    const float* wr = w + d * D_INNC;
    float acc = bias[d];
#pragma unroll
    for (int k = 0; k < D_INNC; ++k) acc += xr[k] * wr[k];
    hb[idx] = f2bf(acc);
}

// ---------------------------------------------------------------------------
// One-shot fp32 -> bf16 convert of ALL four GEMM weight arrays.
// Boundaries (in 8-elem units): Wxz 524288 | Wout 262144 | Wxp 32768 | Wdt 16384.
__global__ __launch_bounds__(256) void wprep_kernel(
    const float* __restrict__ Wxz, const float* __restrict__ Wout,
    const float* __restrict__ Wxp, const float* __restrict__ Wdt,
    u16* __restrict__ wxzb, u16* __restrict__ woutb,
    u16* __restrict__ wxpb, u16* __restrict__ wdtb)
{
    int i = blockIdx.x * 256 + threadIdx.x;     // 0 .. 835583
    const float* src; u16* dst; int off;
    if (i < 524288)      { src = Wxz;  dst = wxzb;  off = i; }
    else if (i < 786432) { src = Wout; dst = woutb; off = i - 524288; }
    else if (i < 819200) { src = Wxp;  dst = wxpb;  off = i - 786432; }
    else                 { src = Wdt;  dst = wdtb;  off = i - 819200; }
    const float* s = src + (size_t)off * 8;
    float4 f0 = *(const float4*)s;
    float4 f1 = *(const float4*)(s + 4);
    float f[8] = {f0.x,f0.y,f0.z,f0.w,f1.x,f1.y,f1.z,f1.w};
    s16x8 hv;
#pragma unroll
    for (int e = 0; e < 8; ++e) hv[e] = (short)f2bf(f[e]);
    *(s16x8*)(dst + (size_t)off * 8) = hv;
}

// ---------------------------------------------------------------------------
// Async-stage one ROWS x 32(u16) K-slice into linear LDS [ROWS][32] via
// global_load_lds width=16. Slot permutation applied on the GLOBAL source
// (linear dest + inverse-swizzled source + swizzled read).
template<int ROWS>
__device__ __forceinline__ void stage_tile(
    const u16* __restrict__ src, int ld, int koff, u16* lds, int t)
{
    const int l = t & 63, w = t >> 6;
    const int r_in = l >> 2, s = l & 3;
#pragma unroll
    for (int p = 0; p < ROWS / 64; ++p) {
        int rb = (p * 4 + w) * 16;            // wave-uniform row base
        int r  = rb + r_in;
        int sw = s ^ ((r ^ (r >> 2)) & 3);    // pre-swizzled source slot
        const u16* g = src + (size_t)r * ld + koff + sw * 8;
        u16* lp = lds + rb * 32;              // uniform per wave
        __builtin_amdgcn_global_load_lds(
            (const GLOBAL_AS void*)g, (LDS_AS void*)lp, 16, 0, 0);
    }
}

// ---------------------------------------------------------------------------
// bf16 MFMA NT GEMM (standalone): swapped-operand mfma(b,a), packed stores.
// MODE 1: xz epilogue — col<1024: bf16 xcb; col>=1024: silu -> bf16 szb.
// MODE 2: bf16 direct out to C0 (ldc).
template<int BM, int BN, int MODE>
__global__ __launch_bounds__(256, 2) void gemm_bf16(
    const u16* __restrict__ A, int lda,
    const u16* __restrict__ B, int ldb,
    void* __restrict__ C0, void* __restrict__ C1,
    int ldc, int K)
{
    constexpr int FM = BM / 32;
    constexpr int FN = BN / 32;
    __shared__ __align__(16) u16 As[2][BM * 32];
    __shared__ __align__(16) u16 Bs[2][BN * 32];

    const int t    = threadIdx.x;
    const int lane = t & 63;
    const int w    = t >> 6;
    const int wm   = (w >> 1) * (BM / 2);
    const int wn   = (w & 1) * (BN / 2);
    const int quad = lane >> 4;
    const int l16  = lane & 15;
    const int m0   = blockIdx.y * BM;
    const int n0   = blockIdx.x * BN;
    const int sq   = (quad ^ ((l16 ^ (l16 >> 2)) & 3)) * 8;

    const u16* Abase = A + (size_t)m0 * lda;
    const u16* Bbase = B + (size_t)n0 * ldb;

    f32x4 acc[FM][FN];
#pragma unroll
    for (int i = 0; i < FM; ++i)
#pragma unroll
        for (int j = 0; j < FN; ++j) acc[i][j] = (f32x4){0.f,0.f,0.f,0.f};

    stage_tile<BM>(Abase, lda, 0, As[0], t);
    stage_tile<BN>(Bbase, ldb, 0, Bs[0], t);

    int cur = 0;
    for (int kk = 0; kk < K; kk += 32) {
        __syncthreads();                    // drains vmcnt: buf[cur] ready
        int kn = kk + 32;
        if (kn < K) {
            stage_tile<BM>(Abase, lda, kn, As[cur ^ 1], t);
            stage_tile<BN>(Bbase, ldb, kn, Bs[cur ^ 1], t);
        }
        s16x8 afr[FM], bfr[FN];
#pragma unroll
        for (int i = 0; i < FM; ++i) {
            int row = wm + i * 16 + l16;
            afr[i] = *(const s16x8*)&As[cur][row * 32 + sq];
        }
#pragma unroll
        for (int j = 0; j < FN; ++j) {
            int row = wn + j * 16 + l16;
            bfr[j] = *(const s16x8*)&Bs[cur][row * 32 + sq];
        }
#pragma unroll
        for (int i = 0; i < FM; ++i)
#pragma unroll
            for (int j = 0; j < FN; ++j)
                acc[i][j] = __builtin_amdgcn_mfma_f32_16x16x32_bf16(bfr[j], afr[i], acc[i][j], 0, 0, 0);
        cur ^= 1;
    }

    if constexpr (MODE == 2) {
        u16* C = (u16*)C0;
#pragma unroll
        for (int i = 0; i < FM; ++i) {
            int m = m0 + wm + i*16 + l16;
#pragma unroll
            for (int j = 0; j < FN; ++j) {
                int nb = n0 + wn + j*16 + quad*4;
                u16x4v o;
#pragma unroll
                for (int r = 0; r < 4; ++r) o[r] = f2bf(acc[i][j][r]);
                *(u16x4v*)&C[(size_t)m * ldc + nb] = o;
            }
        }
    } else {    // MODE 1
        u16* xcb = (u16*)C0;
        u16* szb = (u16*)C1;
#pragma unroll
        for (int i = 0; i < FM; ++i) {
            int m = m0 + wm + i*16 + l16;
#pragma unroll
            for (int j = 0; j < FN; ++j) {
                int nb = n0 + wn + j*16 + quad*4;
                bool isz = nb >= DINNER;
                int cc = nb & (DINNER - 1);
                u16* dst = isz ? szb : xcb;
                u16x4v o;
#pragma unroll
                for (int r = 0; r < 4; ++r) {
                    float v = acc[i][j][r];
                    if (isz) v = v / (1.f + __expf(-v));   // silu(z)
                    o[r] = f2bf(v);
                }
                *(u16x4v*)&dst[(size_t)m * DINNER + cc] = o;
            }
        }
    }
}

// ---------------------------------------------------------------------------
// Fused conv+silu+xp GEMM. Grid (XPSPLIT, MTOT/64). Split p, m-tile by.
__global__ __launch_bounds__(256) void xp_conv_kernel(
    const u16* __restrict__ xcb, const float* __restrict__ cw,
    const float* __restrict__ cb, const u16* __restrict__ wxpL,
    u16* __restrict__ ub, float* __restrict__ xpart)
{
    __shared__ __align__(16) u16 As[64 * 32];
    __shared__ __align__(16) u16 Bs[64 * 32];

    const int t    = threadIdx.x;
    const int lane = t & 63;
    const int w    = t >> 6;
    const int wm   = (w >> 1) * 32;
    const int wn   = (w & 1) * 32;
    const int quad = lane >> 4;
    const int l16  = lane & 15;
    const int p    = blockIdx.x;
    const int m0   = blockIdx.y * 64;
    const int kbase= p * 128;
    const int sq   = (quad ^ ((l16 ^ (l16 >> 2)) & 3)) * 8;

    const int r_st   = t >> 2;
    const int slot   = t & 3;
    const int m_st   = m0 + r_st;
    const int l_st   = m_st & (L_ - 1);
    const int swz    = slot ^ ((r_st ^ (r_st >> 2)) & 3);

    f32x4 acc[2][2];
#pragma unroll
    for (int i = 0; i < 2; ++i)
#pragma unroll
        for (int j = 0; j < 2; ++j) acc[i][j] = (f32x4){0.f,0.f,0.f,0.f};

    for (int ks = 0; ks < 4; ++ks) {
        const int kcol = kbase + ks * 32;
        const int d0   = kcol + slot * 8;
        __syncthreads();        // previous frag reads done; LDS writable
        {   // ---- A-stage: u = silu(conv(xc)+cb) for 8 channels ----
            float a8[8];
            {
                float4 cb0 = *(const float4*)&cb[d0];
                float4 cb1 = *(const float4*)&cb[d0 + 4];
#pragma unroll
                for (int e = 0; e < 4; ++e) { a8[e] = (&cb0.x)[e]; a8[4+e] = (&cb1.x)[e]; }
            }
#pragma unroll
            for (int k = 0; k < 4; ++k) {
                int lag = 3 - k;
                if (l_st >= lag) {
                    s16x8 xv = *(const s16x8*)&xcb[(size_t)(m_st - lag) * DINNER + d0];
#pragma unroll
                    for (int e = 0; e < 8; ++e)
                        a8[e] += bf2f((u16)xv[e]) * cw[(d0 + e) * 4 + k];
                }
            }
            s16x8 hv;
#pragma unroll
            for (int e = 0; e < 8; ++e) {
                float v = a8[e];
                v = v / (1.f + __expf(-v));
                hv[e] = (short)f2bf(v);
            }
            *(s16x8*)&As[r_st * 32 + swz * 8] = hv;           // swizzled LDS
            *(s16x8*)&ub[(size_t)m_st * DINNER + d0] = hv;    // materialize u
        }
        stage_tile<64>(wxpL, DINNER, kcol, Bs, t);            // B async
        __syncthreads();        // ds_writes visible + vmcnt drained

        s16x8 afr[2], bfr[2];
#pragma unroll
        for (int i = 0; i < 2; ++i)
            afr[i] = *(const s16x8*)&As[(wm + i*16 + l16) * 32 + sq];
#pragma unroll
        for (int j = 0; j < 2; ++j)
            bfr[j] = *(const s16x8*)&Bs[(wn + j*16 + l16) * 32 + sq];
#pragma unroll
        for (int i = 0; i < 2; ++i)
#pragma unroll
            for (int j = 0; j < 2; ++j)
                acc[i][j] = __builtin_amdgcn_mfma_f32_16x16x32_bf16(bfr[j], afr[i], acc[i][j], 0, 0, 0);
    }

    float* P = xpart + (size_t)p * MTOT * 64;
#pragma unroll
    for (int i = 0; i < 2; ++i) {
        int m = m0 + wm + i*16 + l16;
#pragma unroll
        for (int j = 0; j < 2; ++j) {
            int nb = wn + j*16 + quad*4;
            float4 o;
            o.x = acc[i][j][0]; o.y = acc[i][j][1];
            o.z = acc[i][j][2]; o.w = acc[i][j][3];
            *(float4*)&P[(size_t)m * 64 + nb] = o;
        }
    }
}

// ---------------------------------------------------------------------------
// Fused xpred + dt GEMM. Grid (DINNER/64, MTOT/64) = (16, 64).
__global__ __launch_bounds__(256) void dt_fused_kernel(
    const float* __restrict__ xpart, const u16* __restrict__ wdtL,
    const float* __restrict__ bdt, u16* __restrict__ dtb,
    float* __restrict__ xdbl)
{
    __shared__ __align__(16) u16 As[64 * 32];
    __shared__ __align__(16) u16 Bs[64 * 32];

    const int t    = threadIdx.x;
    const int lane = t & 63;
    const int w    = t >> 6;
    const int wm   = (w >> 1) * 32;
    const int wn   = (w & 1) * 32;
    const int quad = lane >> 4;
    const int l16  = lane & 15;
    const int n0   = blockIdx.x * 64;
    const int m0   = blockIdx.y * 64;
    const int sq   = (quad ^ ((l16 ^ (l16 >> 2)) & 3)) * 8;

    const int r_st = t >> 2;
    const int slot = t & 3;
    const int swz  = slot ^ ((r_st ^ (r_st >> 2)) & 3);
    const int m_st = m0 + r_st;

    {   // ---- A-stage: dt_lr = bf16(sum partials cols 0..31) ----
        float s8[8];
#pragma unroll
        for (int e = 0; e < 8; ++e) s8[e] = 0.f;
#pragma unroll
        for (int p = 0; p < XPSPLIT; ++p) {
            const float* row = &xpart[((size_t)p * MTOT + m_st) * 64 + slot * 8];
            float4 v0 = *(const float4*)row;
            float4 v1 = *(const float4*)(row + 4);
#pragma unroll
            for (int e = 0; e < 4; ++e) { s8[e] += (&v0.x)[e]; s8[4+e] += (&v1.x)[e]; }
        }
        s16x8 hv;
#pragma unroll
        for (int e = 0; e < 8; ++e) hv[e] = (short)f2bf(s8[e]);
        *(s16x8*)&As[r_st * 32 + swz * 8] = hv;
    }
    stage_tile<64>(wdtL, DTRANK, 0, Bs, t);     // B async (64 x 32 bf16)
    if (blockIdx.x == 0) {  // ---- B/C fp32 sums (cols 32..63) -> xdbl ----
        const int c2 = 32 + slot * 8;
        float s8[8];
#pragma unroll
        for (int e = 0; e < 8; ++e) s8[e] = 0.f;
#pragma unroll
        for (int p = 0; p < XPSPLIT; ++p) {
            const float* row = &xpart[((size_t)p * MTOT + m_st) * 64 + c2];
            float4 v0 = *(const float4*)row;
            float4 v1 = *(const float4*)(row + 4);
#pragma unroll
            for (int e = 0; e < 4; ++e) { s8[e] += (&v0.x)[e]; s8[4+e] += (&v1.x)[e]; }
        }
        float4 o0, o1;
#pragma unroll
        for (int e = 0; e < 4; ++e) { (&o0.x)[e] = s8[e]; (&o1.x)[e] = s8[4+e]; }
        *(float4*)&xdbl[(size_t)m_st * 64 + c2]     = o0;
        *(float4*)&xdbl[(size_t)m_st * 64 + c2 + 4] = o1;
    }
    __syncthreads();

    f32x4 acc[2][2];
#pragma unroll
    for (int i = 0; i < 2; ++i)
#pragma unroll
        for (int j = 0; j < 2; ++j) acc[i][j] = (f32x4){0.f,0.f,0.f,0.f};

    s16x8 afr[2], bfr[2];
#pragma unroll
    for (int i = 0; i < 2; ++i)
        afr[i] = *(const s16x8*)&As[(wm + i*16 + l16) * 32 + sq];
#pragma unroll
    for (int j = 0; j < 2; ++j)
        bfr[j] = *(const s16x8*)&Bs[(wn + j*16 + l16) * 32 + sq];
#pragma unroll
    for (int i = 0; i < 2; ++i)
#pragma unroll
        for (int j = 0; j < 2; ++j)
            acc[i][j] = __builtin_amdgcn_mfma_f32_16x16x32_bf16(bfr[j], afr[i], acc[i][j], 0, 0, 0);

#pragma unroll
    for (int i = 0; i < 2; ++i) {
        int m = m0 + wm + i*16 + l16;
#pragma unroll
        for (int j = 0; j < 2; ++j) {
            int nb = n0 + wn + j*16 + quad*4;
            float4 bb4 = *(const float4*)&bdt[nb];
            u16x4v o;
#pragma unroll
            for (int r = 0; r < 4; ++r) {
                float v = acc[i][j][r] + (&bb4.x)[r];
                float sp = (v > 20.f) ? v : log1pf(__expf(v));
                o[r] = f2bf(sp);
            }
            *(u16x4v*)&dtb[(size_t)m * DINNER + nb] = o;
        }
    }
}

// ---------------------------------------------------------------------------
// Chunked scan pass 1 — one lane per (b,c,d), 16 states in VGPRs.
__global__ __launch_bounds__(256) void scan1_kernel(
    const u16* __restrict__ ub, const float* xdbl,
    const u16* __restrict__ dtb, const float* __restrict__ A_log,
    u16* __restrict__ hfinal, float* __restrict__ dsum)
{
    __shared__ float Bs[CLEN][16];
    const int blk  = blockIdx.x;              // b*256 + c*4 + dblk
    const int dblk = blk & 3;
    const int c    = (blk >> 2) & (CHUNKS - 1);
    const int b    = blk >> 8;
    const int d    = dblk * 256 + threadIdx.x;
    const int mbase = b * L_ + c * CLEN;

    {   // CLEN*16 = 256 entries, one per thread
        int idx = threadIdx.x;
        int tt = idx >> 4, ss = idx & 15;
        Bs[tt][ss] = xdbl[(size_t)(mbase + tt) * 64 + 32 + ss];
    }
    float A[16];
    {
        float4 a4[4];
#pragma unroll
        for (int q = 0; q < 4; ++q) a4[q] = *(const float4*)&A_log[d * 16 + q * 4];
        const float* af = (const float*)a4;
#pragma unroll
        for (int s = 0; s < 16; ++s) A[s] = -__expf(af[s]);
    }
    __syncthreads();

    float h[16];
#pragma unroll
    for (int s = 0; s < 16; ++s) h[s] = 0.f;
    float dts = 0.f;

    for (int t0 = 0; t0 < CLEN; t0 += 8) {
        float dt8[8], u8[8];
#pragma unroll
        for (int j = 0; j < 8; ++j) {
            int m = mbase + t0 + j;
            dt8[j] = bf2f(dtb[(size_t)m * DINNER + d]);
            u8[j]  = bf2f(ub [(size_t)m * DINNER + d]);
        }
#pragma unroll
        for (int j = 0; j < 8; ++j) {
            float dtv = dt8[j], dtu = dtv * u8[j];
            dts += dtv;
            float Bt[16];
#pragma unroll
            for (int q = 0; q < 4; ++q)
                *(float4*)&Bt[q*4] = *(const float4*)&Bs[t0 + j][q*4];
#pragma unroll
            for (int s = 0; s < 16; ++s) {
                float dA = __expf(dtv * A[s]);
                h[s] = dA * h[s] + dtu * Bt[s];
            }
        }
    }
    size_t base = ((size_t)(b * CHUNKS + c) * DINNER + d) * 16;
    s16x8 p0, p1;
#pragma unroll
    for (int s = 0; s < 8; ++s) { p0[s] = (short)f2bf(h[s]); p1[s] = (short)f2bf(h[s+8]); }
    *(s16x8*)&hfinal[base]     = p0;
    *(s16x8*)&hfinal[base + 8] = p1;
    dsum[(size_t)(b * CHUNKS + c) * DINNER + d] = dts;
}

// Pass 2: sequential chunk fix-up (bf16 states, fp32 math).
__global__ __launch_bounds__(256) void scan2_kernel(
    u16* __restrict__ hfinal, const float* __restrict__ dsum,
    const float* __restrict__ A_log)
{
    int t = blockIdx.x * 256 + threadIdx.x;   // 65536 = B_*DINNER*DSTATE
    int s = t & 15, d = (t >> 4) & (DINNER - 1), b = t >> 14;
    float As = -__expf(A_log[d * DSTATE + s]);
    float h = 0.f;
    for (int c0 = 0; c0 < CHUNKS; c0 += 8) {
        float hf8[8], dts8[8];
#pragma unroll
        for (int j = 0; j < 8; ++j) {
            int c = c0 + j;
            size_t i = (size_t)(b * CHUNKS + c) * DINNER + d;
            dts8[j] = dsum[i];
            hf8[j]  = bf2f(hfinal[i * 16 + s]);
        }
#pragma unroll
        for (int j = 0; j < 8; ++j) {
            int c = c0 + j;
            size_t idx = ((size_t)(b * CHUNKS + c) * DINNER + d) * 16 + s;
            hfinal[idx] = f2bf(h);
            h = __expf(As * dts8[j]) * h + hf8[j];
        }
    }
}

// Pass 3: seeded local scan; y = (C.h + u*D)*sz, written bf16.
__global__ __launch_bounds__(256) void scan3_kernel(
    const u16* __restrict__ szb, const u16* __restrict__ ub,
    const float* xdbl, const u16* __restrict__ dtb,
    const float* __restrict__ A_log, const float* __restrict__ Dp,
    const u16* __restrict__ hstart, u16* __restrict__ yb)
{
    __shared__ float Bs[CLEN][16];
    __shared__ float Cs[CLEN][16];
    const int blk  = blockIdx.x;
    const int dblk = blk & 3;
    const int c    = (blk >> 2) & (CHUNKS - 1);
    const int b    = blk >> 8;
    const int d    = dblk * 256 + threadIdx.x;
    const int mbase = b * L_ + c * CLEN;

    {
        int idx = threadIdx.x;
        int tt = idx >> 4, ss = idx & 15;
        Bs[tt][ss] = xdbl[(size_t)(mbase + tt) * 64 + 32 + ss];
        Cs[tt][ss] = xdbl[(size_t)(mbase + tt) * 64 + 48 + ss];
    }
    float A[16];
    {
        float4 a4[4];
#pragma unroll
        for (int q = 0; q < 4; ++q) a4[q] = *(const float4*)&A_log[d * 16 + q * 4];
        const float* af = (const float*)a4;
#pragma unroll
        for (int s = 0; s < 16; ++s) A[s] = -__expf(af[s]);
    }
    const float Dval = Dp[d];

    float h[16];
    {
        size_t base = ((size_t)(b * CHUNKS + c) * DINNER + d) * 16;
        s16x8 p0 = *(const s16x8*)&hstart[base];
        s16x8 p1 = *(const s16x8*)&hstart[base + 8];
#pragma unroll
        for (int s = 0; s < 8; ++s) { h[s] = bf2f((u16)p0[s]); h[s+8] = bf2f((u16)p1[s]); }
    }
    __syncthreads();

    for (int t0 = 0; t0 < CLEN; t0 += 8) {
        float dt8[8], u8[8], sz8[8];
#pragma unroll
        for (int j = 0; j < 8; ++j) {
            int m = mbase + t0 + j;
            dt8[j] = bf2f(dtb[(size_t)m * DINNER + d]);
            u8[j]  = bf2f(ub [(size_t)m * DINNER + d]);
            sz8[j] = bf2f(szb[(size_t)m * DINNER + d]);
        }
#pragma unroll
        for (int j = 0; j < 8; ++j) {
            float dtv = dt8[j], dtu = dtv * u8[j];
            float Bt[16], Ct[16];
#pragma unroll
            for (int q = 0; q < 4; ++q) {
                *(float4*)&Bt[q*4] = *(const float4*)&Bs[t0 + j][q*4];
                *(float4*)&Ct[q*4] = *(const float4*)&Cs[t0 + j][q*4];
            }
            float yv = 0.f;
#pragma unroll
            for (int s = 0; s < 16; ++s) {
                float dA = __expf(dtv * A[s]);
                h[s] = dA * h[s] + dtu * Bt[s];
                yv += h[s] * Ct[s];
            }
            int m = mbase + t0 + j;
            yb[(size_t)m * DINNER + d] = f2bf((yv + u8[j] * Dval) * sz8[j]);
        }
    }
}

// ---------------------------------------------------------------------------
// Final LayerNorm over DMODEL=512, reading bf16 h.
__global__ __launch_bounds__(256) void ln_kernel(
    const u16* __restrict__ hb, const float* __restrict__ g,
    const float* __restrict__ bta, float* __restrict__ out)
{
    int m = blockIdx.x;
    size_t base = (size_t)m * DMODEL;
    int t = threadIdx.x;
    float v0 = bf2f(hb[base + t]);
    float v1 = bf2f(hb[base + t + 256]);
    float sum = v0 + v1, sq = v0*v0 + v1*v1;
#pragma unroll
    for (int off = 32; off; off >>= 1) {
        sum += __shfl_down(sum, off);
        sq  += __shfl_down(sq,  off);
    }
    __shared__ float ls[4], lq[4];
    int w = t >> 6;
    if ((t & 63) == 0) { ls[w] = sum; lq[w] = sq; }
    __syncthreads();
    sum = ls[0] + ls[1] + ls[2] + ls[3];
    sq  = lq[0] + lq[1] + lq[2] + lq[3];
    float mu  = sum * (1.f / DMODEL);
    float var = sq * (1.f / DMODEL) - mu * mu;
    float rs  = rsqrtf(var + 1e-5f);
    out[base + t]       = (v0 - mu) * rs * g[t]       + bta[t];
    out[base + t + 256] = (v1 - mu) * rs * g[t + 256] + bta[t + 256];
}

// ---------------------------------------------------------------------------
extern "C" void kernel_launch(void* const* d_in, const int* in_sizes, int n_in,
                              void* d_out, int out_size, void* d_ws, size_t ws_size,
                              hipStream_t stream)
{
    const float* x      = (const float*)d_in[0];
    const float* in_w   = (const float*)d_in[1];
    const float* in_b   = (const float*)d_in[2];
    const float* W_xz   = (const float*)d_in[3];
    const float* conv_w = (const float*)d_in[4];
    const float* conv_b = (const float*)d_in[5];
    const float* W_xp   = (const float*)d_in[6];
    const float* W_dt   = (const float*)d_in[7];
    const float* b_dt   = (const float*)d_in[8];
    const float* A_log  = (const float*)d_in[9];
    const float* D_par  = (const float*)d_in[10];
    const float* W_out  = (const float*)d_in[11];
    const float* ln_g   = (const float*)d_in[12];
    const float* ln_b   = (const float*)d_in[13];
    float* out = (float*)d_out;

    // Workspace layout (floats), total ~19 M floats = 76 MB.
    float* ws      = (float*)d_ws;
    float* hbF     = ws;                    // 1 M   : hb bf16 (2M u16)
    float* hfinF   = hbF    + 1048576;      // 2 M   : hfinal bf16 (4M u16)
    float* xcbF    = hfinF  + 2097152;      // 2 M   : xc bf16
    float* szbF    = xcbF   + 2097152;      // 2 M   : silu(z) bf16
    float* ubF     = szbF   + 2097152;      // 2 M   : u bf16
    float* xdbl    = ubF    + 2097152;      // 256 K : fp32 (B/C in cols 32..63)
    float* dtbF    = xdbl   + 262144;       // 2 M   : dt bf16
    float* ybF     = dtbF   + 2097152;      // 2 M   : y bf16
    float* wxzF    = ybF    + 2097152;      // 2 M   : Wxz bf16, all layers
    float* woutF   = wxzF   + 2097152;      // 1 M   : Wout bf16, all layers
    float* wxpF    = woutF  + 1048576;      // 128 K : Wxp bf16, all layers
    float* wdtF    = wxpF   + 131072;       // 64 K  : Wdt bf16, all layers
    float* dsum    = wdtF   + 65536;        // 256 K : per-chunk dt sums fp32
    float* xpart   = dsum   + 262144;       // 2 M   : xp K-split partials fp32

    u16* hb     = (u16*)hbF;
    u16* hfinal = (u16*)hfinF;
    u16* xcb  = (u16*)xcbF;
    u16* szb  = (u16*)szbF;
    u16* ub   = (u16*)ubF;
    u16* dtb  = (u16*)dtbF;
    u16* yb   = (u16*)ybF;
    u16* wxzb  = (u16*)wxzF;
    u16* woutb = (u16*)woutF;
    u16* wxpb  = (u16*)wxpF;
    u16* wdtb  = (u16*)wdtF;

    // One-time weight prep (single dispatch).
    wprep_kernel<<<3264, 256, 0, stream>>>(W_xz, W_out, W_xp, W_dt,
                                           wxzb, woutb, wxpb, wdtb);

    in_proj_kernel<<<MTOT*DMODEL/256, 256, 0, stream>>>(x, in_w, in_b, hb);

    for (int layer = 0; layer < DEPTH_; ++layer) {
        const float* cw    = conv_w + (size_t)layer * DINNER * DCONV;
        const float* cb    = conv_b + (size_t)layer * DINNER;
        const float* bdt   = b_dt   + (size_t)layer * DINNER;
        const float* Alog  = A_log  + (size_t)layer * DINNER * DSTATE;
        const float* Dp    = D_par  + (size_t)layer * DINNER;
        const u16* wxzL    = wxzb  + (size_t)layer * 2048 * DMODEL;
        const u16* woutL   = woutb + (size_t)layer * DMODEL * DINNER;
        const u16* wxpL    = wxpb  + (size_t)layer * 64 * DINNER;
        const u16* wdtL    = wdtb  + (size_t)layer * DINNER * DTRANK;

        // xz GEMM (single, back to normal)
        gemm_bf16<128,128,1><<<dim3(2048/128, MTOT/128), 256, 0, stream>>>(
            hb, DMODEL, wxzL, DMODEL, xcb, szb, 0, DMODEL);
        // fused conv+silu+xp — LAUNCHED TWICE (diagnostic: pure/idempotent)
        xp_conv_kernel<<<dim3(XPSPLIT, MTOT/64), 256, 0, stream>>>(
            xcb, cw, cb, wxpL, ub, xpart);
        xp_conv_kernel<<<dim3(XPSPLIT, MTOT/64), 256, 0, stream>>>(
            xcb, cw, cb, wxpL, ub, xpart);
        // fused xpred+dt GEMM — LAUNCHED TWICE (diagnostic: pure/idempotent)
        dt_fused_kernel<<<dim3(DINNER/64, MTOT/64), 256, 0, stream>>>(
            xpart, wdtL, bdt, dtb, xdbl);
        dt_fused_kernel<<<dim3(DINNER/64, MTOT/64), 256, 0, stream>>>(
            xpart, wdtL, bdt, dtb, xdbl);
        // scan1 — LAUNCHED TWICE (pure; both BEFORE scan2, which mutates hfinal)
        scan1_kernel<<<B_*CHUNKS*(DINNER/256), 256, 0, stream>>>(ub, xdbl, dtb, Alog, hfinal, dsum);
        scan1_kernel<<<B_*CHUNKS*(DINNER/256), 256, 0, stream>>>(ub, xdbl, dtb, Alog, hfinal, dsum);
        scan2_kernel<<<(B_*DINNER*DSTATE)/256, 256, 0, stream>>>(hfinal, dsum, Alog);
        // scan3 — LAUNCHED TWICE (pure)
        scan3_kernel<<<B_*CHUNKS*(DINNER/256), 256, 0, stream>>>(szb, ub, xdbl, dtb, Alog, Dp, hfinal, yb);
        scan3_kernel<<<B_*CHUNKS*(DINNER/256), 256, 0, stream>>>(szb, ub, xdbl, dtb, Alog, Dp, hfinal, yb);
        // out GEMM (single)
        gemm_bf16<64,64,2><<<dim3(DMODEL/64, MTOT/64), 256, 0, stream>>>(
            yb, DINNER, woutL, DINNER, hb, nullptr, DMODEL, DINNER);
    }

    ln_kernel<<<MTOT, 256, 0, stream>>>(hb, ln_g, ln_b, out);
}

// Round 13
// 551.440 us; speedup vs baseline: 1.5851x; 1.5851x over previous
//
#include <hip/hip_runtime.h>
#include <math.h>

// Problem constants (match reference)
#define B_      4
#define L_      1024
#define D_INNC  8      // D_IN
#define DMODEL  512
#define DEPTH_  4
#define DINNER  1024
#define DSTATE  16
#define DCONV   4
#define DTRANK  32
#define MTOT    (B_*L_)   // 4096
#define CHUNKS  64
#define CLEN    16        // L_/CHUNKS
#define XPSPLIT 8         // xp GEMM K-splits (K=1024 -> 8 x 128)

typedef float f32x4 __attribute__((ext_vector_type(4)));
typedef short s16x8 __attribute__((ext_vector_type(8)));
typedef unsigned short u16;
typedef unsigned short u16x4v __attribute__((ext_vector_type(4)));

#define GLOBAL_AS __attribute__((address_space(1)))
#define LDS_AS    __attribute__((address_space(3)))

// fp32 -> bf16 round-to-nearest-even
__device__ __forceinline__ u16 f2bf(float v) {
    unsigned b = __float_as_uint(v);
    return (u16)((b + 0x7FFF + ((b >> 16) & 1)) >> 16);
}
__device__ __forceinline__ float bf2f(u16 h) {
    return __uint_as_float((unsigned)h << 16);
}

// ---------------------------------------------------------------------------
// h = x @ in_w^T + in_b  -> bf16 (4096 x 512, K=8)
__global__ __launch_bounds__(256) void in_proj_kernel(
    const float* __restrict__ x, const float* __restrict__ w,
    const float* __restrict__ bias, u16* __restrict__ hb)
{
    int idx = blockIdx.x * 256 + threadIdx.x;
    int m = idx / DMODEL, d = idx % DMODEL;
    const float* xr = x + m * D_INNC;
    const float* wr = w + d * D_INNC;
    float acc = bias[d];
#pragma unroll
    for (int k = 0; k < D_INNC; ++k) acc += xr[k] * wr[k];
    hb[idx] = f2bf(acc);
}

// ---------------------------------------------------------------------------
// One-shot fp32 -> bf16 convert of ALL four GEMM weight arrays.
// Boundaries (in 8-elem units): Wxz 524288 | Wout 262144 | Wxp 32768 | Wdt 16384.
__global__ __launch_bounds__(256) void wprep_kernel(
    const float* __restrict__ Wxz, const float* __restrict__ Wout,
    const float* __restrict__ Wxp, const float* __restrict__ Wdt,
    u16* __restrict__ wxzb, u16* __restrict__ woutb,
    u16* __restrict__ wxpb, u16* __restrict__ wdtb)
{
    int i = blockIdx.x * 256 + threadIdx.x;     // 0 .. 835583
    const float* src; u16* dst; int off;
    if (i < 524288)      { src = Wxz;  dst = wxzb;  off = i; }
    else if (i < 786432) { src = Wout; dst = woutb; off = i - 524288; }
    else if (i < 819200) { src = Wxp;  dst = wxpb;  off = i - 786432; }
    else                 { src = Wdt;  dst = wdtb;  off = i - 819200; }
    const float* s = src + (size_t)off * 8;
    float4 f0 = *(const float4*)s;
    float4 f1 = *(const float4*)(s + 4);
    float f[8] = {f0.x,f0.y,f0.z,f0.w,f1.x,f1.y,f1.z,f1.w};
    s16x8 hv;
#pragma unroll
    for (int e = 0; e < 8; ++e) hv[e] = (short)f2bf(f[e]);
    *(s16x8*)(dst + (size_t)off * 8) = hv;
}

// ---------------------------------------------------------------------------
// Async-stage one ROWS x 32(u16) K-slice into linear LDS [ROWS][32] via
// global_load_lds width=16. Slot permutation applied on the GLOBAL source
// (linear dest + inverse-swizzled source + swizzled read).
template<int ROWS>
__device__ __forceinline__ void stage_tile(
    const u16* __restrict__ src, int ld, int koff, u16* lds, int t)
{
    const int l = t & 63, w = t >> 6;
    const int r_in = l >> 2, s = l & 3;
#pragma unroll
    for (int p = 0; p < ROWS / 64; ++p) {
        int rb = (p * 4 + w) * 16;            // wave-uniform row base
        int r  = rb + r_in;
        int sw = s ^ ((r ^ (r >> 2)) & 3);    // pre-swizzled source slot
        const u16* g = src + (size_t)r * ld + koff + sw * 8;
        u16* lp = lds + rb * 32;              // uniform per wave
        __builtin_amdgcn_global_load_lds(
            (const GLOBAL_AS void*)g, (LDS_AS void*)lp, 16, 0, 0);
    }
}

// ---------------------------------------------------------------------------
// bf16 MFMA NT GEMM (standalone): swapped-operand mfma(b,a), packed stores.
// MODE 1: xz epilogue — col<1024: bf16 xcb; col>=1024: silu -> bf16 szb.
// MODE 2: bf16 direct out to C0 (ldc).
template<int BM, int BN, int MODE>
__global__ __launch_bounds__(256, 2) void gemm_bf16(
    const u16* __restrict__ A, int lda,
    const u16* __restrict__ B, int ldb,
    void* __restrict__ C0, void* __restrict__ C1,
    int ldc, int K)
{
    constexpr int FM = BM / 32;
    constexpr int FN = BN / 32;
    __shared__ __align__(16) u16 As[2][BM * 32];
    __shared__ __align__(16) u16 Bs[2][BN * 32];

    const int t    = threadIdx.x;
    const int lane = t & 63;
    const int w    = t >> 6;
    const int wm   = (w >> 1) * (BM / 2);
    const int wn   = (w & 1) * (BN / 2);
    const int quad = lane >> 4;
    const int l16  = lane & 15;
    const int m0   = blockIdx.y * BM;
    const int n0   = blockIdx.x * BN;
    const int sq   = (quad ^ ((l16 ^ (l16 >> 2)) & 3)) * 8;

    const u16* Abase = A + (size_t)m0 * lda;
    const u16* Bbase = B + (size_t)n0 * ldb;

    f32x4 acc[FM][FN];
#pragma unroll
    for (int i = 0; i < FM; ++i)
#pragma unroll
        for (int j = 0; j < FN; ++j) acc[i][j] = (f32x4){0.f,0.f,0.f,0.f};

    stage_tile<BM>(Abase, lda, 0, As[0], t);
    stage_tile<BN>(Bbase, ldb, 0, Bs[0], t);

    int cur = 0;
    for (int kk = 0; kk < K; kk += 32) {
        __syncthreads();                    // drains vmcnt: buf[cur] ready
        int kn = kk + 32;
        if (kn < K) {
            stage_tile<BM>(Abase, lda, kn, As[cur ^ 1], t);
            stage_tile<BN>(Bbase, ldb, kn, Bs[cur ^ 1], t);
        }
        s16x8 afr[FM], bfr[FN];
#pragma unroll
        for (int i = 0; i < FM; ++i) {
            int row = wm + i * 16 + l16;
            afr[i] = *(const s16x8*)&As[cur][row * 32 + sq];
        }
#pragma unroll
        for (int j = 0; j < FN; ++j) {
            int row = wn + j * 16 + l16;
            bfr[j] = *(const s16x8*)&Bs[cur][row * 32 + sq];
        }
#pragma unroll
        for (int i = 0; i < FM; ++i)
#pragma unroll
            for (int j = 0; j < FN; ++j)
                acc[i][j] = __builtin_amdgcn_mfma_f32_16x16x32_bf16(bfr[j], afr[i], acc[i][j], 0, 0, 0);
        cur ^= 1;
    }

    if constexpr (MODE == 2) {
        u16* C = (u16*)C0;
#pragma unroll
        for (int i = 0; i < FM; ++i) {
            int m = m0 + wm + i*16 + l16;
#pragma unroll
            for (int j = 0; j < FN; ++j) {
                int nb = n0 + wn + j*16 + quad*4;
                u16x4v o;
#pragma unroll
                for (int r = 0; r < 4; ++r) o[r] = f2bf(acc[i][j][r]);
                *(u16x4v*)&C[(size_t)m * ldc + nb] = o;
            }
        }
    } else {    // MODE 1
        u16* xcb = (u16*)C0;
        u16* szb = (u16*)C1;
#pragma unroll
        for (int i = 0; i < FM; ++i) {
            int m = m0 + wm + i*16 + l16;
#pragma unroll
            for (int j = 0; j < FN; ++j) {
                int nb = n0 + wn + j*16 + quad*4;
                bool isz = nb >= DINNER;
                int cc = nb & (DINNER - 1);
                u16* dst = isz ? szb : xcb;
                u16x4v o;
#pragma unroll
                for (int r = 0; r < 4; ++r) {
                    float v = acc[i][j][r];
                    if (isz) v = v / (1.f + __expf(-v));   // silu(z)
                    o[r] = f2bf(v);
                }
                *(u16x4v*)&dst[(size_t)m * DINNER + cc] = o;
            }
        }
    }
}

// ---------------------------------------------------------------------------
// Fused conv+silu+xp GEMM. Grid (XPSPLIT, MTOT/64). Split p, m-tile by.
// cw/cb for this split's 128 channels staged in LDS once (were 128 scalar
// global gathers per thread).
__global__ __launch_bounds__(256) void xp_conv_kernel(
    const u16* __restrict__ xcb, const float* __restrict__ cw,
    const float* __restrict__ cb, const u16* __restrict__ wxpL,
    u16* __restrict__ ub, float* __restrict__ xpart)
{
    __shared__ __align__(16) u16 As[64 * 32];
    __shared__ __align__(16) u16 Bs[64 * 32];
    __shared__ __align__(16) float cws[512];   // cw[kbase..kbase+128)[4]
    __shared__ __align__(16) float cbs[128];   // cb[kbase..kbase+128)

    const int t    = threadIdx.x;
    const int lane = t & 63;
    const int w    = t >> 6;
    const int wm   = (w >> 1) * 32;
    const int wn   = (w & 1) * 32;
    const int quad = lane >> 4;
    const int l16  = lane & 15;
    const int p    = blockIdx.x;
    const int m0   = blockIdx.y * 64;
    const int kbase= p * 128;
    const int sq   = (quad ^ ((l16 ^ (l16 >> 2)) & 3)) * 8;

    const int r_st   = t >> 2;
    const int slot   = t & 3;
    const int m_st   = m0 + r_st;
    const int l_st   = m_st & (L_ - 1);
    const int swz    = slot ^ ((r_st ^ (r_st >> 2)) & 3);

    if (t < 128) *(float4*)&cws[t*4] = *(const float4*)&cw[(size_t)kbase*4 + t*4];
    if (t >= 128 && t < 160) {
        int i = t - 128;
        *(float4*)&cbs[i*4] = *(const float4*)&cb[kbase + i*4];
    }

    f32x4 acc[2][2];
#pragma unroll
    for (int i = 0; i < 2; ++i)
#pragma unroll
        for (int j = 0; j < 2; ++j) acc[i][j] = (f32x4){0.f,0.f,0.f,0.f};

    for (int ks = 0; ks < 4; ++ks) {
        const int kcol = kbase + ks * 32;
        const int dl0  = ks * 32 + slot * 8;    // tile-local channel base
        const int d0   = kcol + slot * 8;
        __syncthreads();        // LDS writable (and cws/cbs visible on ks=0)
        {   // ---- A-stage: u = silu(conv(xc)+cb) for 8 channels ----
            float a8[8];
#pragma unroll
            for (int e = 0; e < 8; ++e) a8[e] = cbs[dl0 + e];
#pragma unroll
            for (int k = 0; k < 4; ++k) {
                int lag = 3 - k;
                if (l_st >= lag) {
                    s16x8 xv = *(const s16x8*)&xcb[(size_t)(m_st - lag) * DINNER + d0];
#pragma unroll
                    for (int e = 0; e < 8; ++e)
                        a8[e] += bf2f((u16)xv[e]) * cws[(dl0 + e) * 4 + k];
                }
            }
            s16x8 hv;
#pragma unroll
            for (int e = 0; e < 8; ++e) {
                float v = a8[e];
                v = v / (1.f + __expf(-v));
                hv[e] = (short)f2bf(v);
            }
            *(s16x8*)&As[r_st * 32 + swz * 8] = hv;           // swizzled LDS
            *(s16x8*)&ub[(size_t)m_st * DINNER + d0] = hv;    // materialize u
        }
        stage_tile<64>(wxpL, DINNER, kcol, Bs, t);            // B async
        __syncthreads();        // ds_writes visible + vmcnt drained

        s16x8 afr[2], bfr[2];
#pragma unroll
        for (int i = 0; i < 2; ++i)
            afr[i] = *(const s16x8*)&As[(wm + i*16 + l16) * 32 + sq];
#pragma unroll
        for (int j = 0; j < 2; ++j)
            bfr[j] = *(const s16x8*)&Bs[(wn + j*16 + l16) * 32 + sq];
#pragma unroll
        for (int i = 0; i < 2; ++i)
#pragma unroll
            for (int j = 0; j < 2; ++j)
                acc[i][j] = __builtin_amdgcn_mfma_f32_16x16x32_bf16(bfr[j], afr[i], acc[i][j], 0, 0, 0);
    }

    float* P = xpart + (size_t)p * MTOT * 64;
#pragma unroll
    for (int i = 0; i < 2; ++i) {
        int m = m0 + wm + i*16 + l16;
#pragma unroll
        for (int j = 0; j < 2; ++j) {
            int nb = wn + j*16 + quad*4;
            float4 o;
            o.x = acc[i][j][0]; o.y = acc[i][j][1];
            o.z = acc[i][j][2]; o.w = acc[i][j][3];
            *(float4*)&P[(size_t)m * 64 + nb] = o;
        }
    }
}

// ---------------------------------------------------------------------------
// Fused xpred + dt GEMM. Grid (DINNER/64, MTOT/64) = (16, 64).
__global__ __launch_bounds__(256) void dt_fused_kernel(
    const float* __restrict__ xpart, const u16* __restrict__ wdtL,
    const float* __restrict__ bdt, u16* __restrict__ dtb,
    float* __restrict__ xdbl)
{
    __shared__ __align__(16) u16 As[64 * 32];
    __shared__ __align__(16) u16 Bs[64 * 32];

    const int t    = threadIdx.x;
    const int lane = t & 63;
    const int w    = t >> 6;
    const int wm   = (w >> 1) * 32;
    const int wn   = (w & 1) * 32;
    const int quad = lane >> 4;
    const int l16  = lane & 15;
    const int n0   = blockIdx.x * 64;
    const int m0   = blockIdx.y * 64;
    const int sq   = (quad ^ ((l16 ^ (l16 >> 2)) & 3)) * 8;

    const int r_st = t >> 2;
    const int slot = t & 3;
    const int swz  = slot ^ ((r_st ^ (r_st >> 2)) & 3);
    const int m_st = m0 + r_st;

    {   // ---- A-stage: dt_lr = bf16(sum partials cols 0..31) ----
        float s8[8];
#pragma unroll
        for (int e = 0; e < 8; ++e) s8[e] = 0.f;
#pragma unroll
        for (int p = 0; p < XPSPLIT; ++p) {
            const float* row = &xpart[((size_t)p * MTOT + m_st) * 64 + slot * 8];
            float4 v0 = *(const float4*)row;
            float4 v1 = *(const float4*)(row + 4);
#pragma unroll
            for (int e = 0; e < 4; ++e) { s8[e] += (&v0.x)[e]; s8[4+e] += (&v1.x)[e]; }
        }
        s16x8 hv;
#pragma unroll
        for (int e = 0; e < 8; ++e) hv[e] = (short)f2bf(s8[e]);
        *(s16x8*)&As[r_st * 32 + swz * 8] = hv;
    }
    stage_tile<64>(wdtL, DTRANK, 0, Bs, t);     // B async (64 x 32 bf16)
    if (blockIdx.x == 0) {  // ---- B/C fp32 sums (cols 32..63) -> xdbl ----
        const int c2 = 32 + slot * 8;
        float s8[8];
#pragma unroll
        for (int e = 0; e < 8; ++e) s8[e] = 0.f;
#pragma unroll
        for (int p = 0; p < XPSPLIT; ++p) {
            const float* row = &xpart[((size_t)p * MTOT + m_st) * 64 + c2];
            float4 v0 = *(const float4*)row;
            float4 v1 = *(const float4*)(row + 4);
#pragma unroll
            for (int e = 0; e < 4; ++e) { s8[e] += (&v0.x)[e]; s8[4+e] += (&v1.x)[e]; }
        }
        float4 o0, o1;
#pragma unroll
        for (int e = 0; e < 4; ++e) { (&o0.x)[e] = s8[e]; (&o1.x)[e] = s8[4+e]; }
        *(float4*)&xdbl[(size_t)m_st * 64 + c2]     = o0;
        *(float4*)&xdbl[(size_t)m_st * 64 + c2 + 4] = o1;
    }
    __syncthreads();

    f32x4 acc[2][2];
#pragma unroll
    for (int i = 0; i < 2; ++i)
#pragma unroll
        for (int j = 0; j < 2; ++j) acc[i][j] = (f32x4){0.f,0.f,0.f,0.f};

    s16x8 afr[2], bfr[2];
#pragma unroll
    for (int i = 0; i < 2; ++i)
        afr[i] = *(const s16x8*)&As[(wm + i*16 + l16) * 32 + sq];
#pragma unroll
    for (int j = 0; j < 2; ++j)
        bfr[j] = *(const s16x8*)&Bs[(wn + j*16 + l16) * 32 + sq];
#pragma unroll
    for (int i = 0; i < 2; ++i)
#pragma unroll
        for (int j = 0; j < 2; ++j)
            acc[i][j] = __builtin_amdgcn_mfma_f32_16x16x32_bf16(bfr[j], afr[i], acc[i][j], 0, 0, 0);

#pragma unroll
    for (int i = 0; i < 2; ++i) {
        int m = m0 + wm + i*16 + l16;
#pragma unroll
        for (int j = 0; j < 2; ++j) {
            int nb = n0 + wn + j*16 + quad*4;
            float4 bb4 = *(const float4*)&bdt[nb];
            u16x4v o;
#pragma unroll
            for (int r = 0; r < 4; ++r) {
                float v = acc[i][j][r] + (&bb4.x)[r];
                float sp = (v > 20.f) ? v : log1pf(__expf(v));
                o[r] = f2bf(sp);
            }
            *(u16x4v*)&dtb[(size_t)m * DINNER + nb] = o;
        }
    }
}

// ---------------------------------------------------------------------------
// Chunked scan pass 1 — u/dt tiles staged in LDS via coalesced s16x8 loads
// (was 32 scalar 2B global loads per thread).
__global__ __launch_bounds__(256) void scan1_kernel(
    const u16* __restrict__ ub, const float* xdbl,
    const u16* __restrict__ dtb, const float* __restrict__ A_log,
    u16* __restrict__ hfinal, float* __restrict__ dsum)
{
    __shared__ __align__(16) u16 Ut[CLEN][256];
    __shared__ __align__(16) u16 Dt[CLEN][256];
    __shared__ float Bs[CLEN][16];
    const int blk  = blockIdx.x;              // b*256 + c*4 + dblk
    const int dblk = blk & 3;
    const int c    = (blk >> 2) & (CHUNKS - 1);
    const int b    = blk >> 8;
    const int tid  = threadIdx.x;
    const int d    = dblk * 256 + tid;
    const int dbase= dblk * 256;
    const int mbase = b * L_ + c * CLEN;

#pragma unroll
    for (int q = 0; q < 2; ++q) {   // 16 rows x 256 cols, s16x8 per thread
        int i = (q * 256 + tid) * 8;
        int row = i >> 8, col = i & 255;
        *(s16x8*)&Ut[row][col] = *(const s16x8*)&ub [(size_t)(mbase + row) * DINNER + dbase + col];
        *(s16x8*)&Dt[row][col] = *(const s16x8*)&dtb[(size_t)(mbase + row) * DINNER + dbase + col];
    }
    {
        int tt = tid >> 4, ss = tid & 15;
        Bs[tt][ss] = xdbl[(size_t)(mbase + tt) * 64 + 32 + ss];
    }
    float A[16];
    {
        float4 a4[4];
#pragma unroll
        for (int q = 0; q < 4; ++q) a4[q] = *(const float4*)&A_log[d * 16 + q * 4];
        const float* af = (const float*)a4;
#pragma unroll
        for (int s = 0; s < 16; ++s) A[s] = -__expf(af[s]);
    }
    __syncthreads();

    float h[16];
#pragma unroll
    for (int s = 0; s < 16; ++s) h[s] = 0.f;
    float dts = 0.f;

    for (int t0 = 0; t0 < CLEN; t0 += 8) {
#pragma unroll
        for (int j = 0; j < 8; ++j) {
            float dtv = bf2f(Dt[t0 + j][tid]);
            float uv  = bf2f(Ut[t0 + j][tid]);
            float dtu = dtv * uv;
            dts += dtv;
            float Bt[16];
#pragma unroll
            for (int q = 0; q < 4; ++q)
                *(float4*)&Bt[q*4] = *(const float4*)&Bs[t0 + j][q*4];
#pragma unroll
            for (int s = 0; s < 16; ++s) {
                float dA = __expf(dtv * A[s]);
                h[s] = dA * h[s] + dtu * Bt[s];
            }
        }
    }
    size_t base = ((size_t)(b * CHUNKS + c) * DINNER + d) * 16;
    s16x8 p0, p1;
#pragma unroll
    for (int s = 0; s < 8; ++s) { p0[s] = (short)f2bf(h[s]); p1[s] = (short)f2bf(h[s+8]); }
    *(s16x8*)&hfinal[base]     = p0;
    *(s16x8*)&hfinal[base + 8] = p1;
    dsum[(size_t)(b * CHUNKS + c) * DINNER + d] = dts;
}

// Pass 2: sequential chunk fix-up (bf16 states, fp32 math).
__global__ __launch_bounds__(256) void scan2_kernel(
    u16* __restrict__ hfinal, const float* __restrict__ dsum,
    const float* __restrict__ A_log)
{
    int t = blockIdx.x * 256 + threadIdx.x;   // 65536 = B_*DINNER*DSTATE
    int s = t & 15, d = (t >> 4) & (DINNER - 1), b = t >> 14;
    float As = -__expf(A_log[d * DSTATE + s]);
    float h = 0.f;
    for (int c0 = 0; c0 < CHUNKS; c0 += 8) {
        float hf8[8], dts8[8];
#pragma unroll
        for (int j = 0; j < 8; ++j) {
            int c = c0 + j;
            size_t i = (size_t)(b * CHUNKS + c) * DINNER + d;
            dts8[j] = dsum[i];
            hf8[j]  = bf2f(hfinal[i * 16 + s]);
        }
#pragma unroll
        for (int j = 0; j < 8; ++j) {
            int c = c0 + j;
            size_t idx = ((size_t)(b * CHUNKS + c) * DINNER + d) * 16 + s;
            hfinal[idx] = f2bf(h);
            h = __expf(As * dts8[j]) * h + hf8[j];
        }
    }
}

// Pass 3: seeded local scan; u/dt/sz tiles staged in LDS (coalesced).
__global__ __launch_bounds__(256) void scan3_kernel(
    const u16* __restrict__ szb, const u16* __restrict__ ub,
    const float* xdbl, const u16* __restrict__ dtb,
    const float* __restrict__ A_log, const float* __restrict__ Dp,
    const u16* __restrict__ hstart, u16* __restrict__ yb)
{
    __shared__ __align__(16) u16 Ut[CLEN][256];
    __shared__ __align__(16) u16 Dt[CLEN][256];
    __shared__ __align__(16) u16 St[CLEN][256];
    __shared__ float Bs[CLEN][16];
    __shared__ float Cs[CLEN][16];
    const int blk  = blockIdx.x;
    const int dblk = blk & 3;
    const int c    = (blk >> 2) & (CHUNKS - 1);
    const int b    = blk >> 8;
    const int tid  = threadIdx.x;
    const int d    = dblk * 256 + tid;
    const int dbase= dblk * 256;
    const int mbase = b * L_ + c * CLEN;

#pragma unroll
    for (int q = 0; q < 2; ++q) {
        int i = (q * 256 + tid) * 8;
        int row = i >> 8, col = i & 255;
        *(s16x8*)&Ut[row][col] = *(const s16x8*)&ub [(size_t)(mbase + row) * DINNER + dbase + col];
        *(s16x8*)&Dt[row][col] = *(const s16x8*)&dtb[(size_t)(mbase + row) * DINNER + dbase + col];
        *(s16x8*)&St[row][col] = *(const s16x8*)&szb[(size_t)(mbase + row) * DINNER + dbase + col];
    }
    {
        int tt = tid >> 4, ss = tid & 15;
        Bs[tt][ss] = xdbl[(size_t)(mbase + tt) * 64 + 32 + ss];
        Cs[tt][ss] = xdbl[(size_t)(mbase + tt) * 64 + 48 + ss];
    }
    float A[16];
    {
        float4 a4[4];
#pragma unroll
        for (int q = 0; q < 4; ++q) a4[q] = *(const float4*)&A_log[d * 16 + q * 4];
        const float* af = (const float*)a4;
#pragma unroll
        for (int s = 0; s < 16; ++s) A[s] = -__expf(af[s]);
    }
    const float Dval = Dp[d];

    float h[16];
    {
        size_t base = ((size_t)(b * CHUNKS + c) * DINNER + d) * 16;
        s16x8 p0 = *(const s16x8*)&hstart[base];
        s16x8 p1 = *(const s16x8*)&hstart[base + 8];
#pragma unroll
        for (int s = 0; s < 8; ++s) { h[s] = bf2f((u16)p0[s]); h[s+8] = bf2f((u16)p1[s]); }
    }
    __syncthreads();

    for (int t0 = 0; t0 < CLEN; t0 += 8) {
#pragma unroll
        for (int j = 0; j < 8; ++j) {
            float dtv = bf2f(Dt[t0 + j][tid]);
            float uv  = bf2f(Ut[t0 + j][tid]);
            float szv = bf2f(St[t0 + j][tid]);
            float dtu = dtv * uv;
            float Bt[16], Ct[16];
#pragma unroll
            for (int q = 0; q < 4; ++q) {
                *(float4*)&Bt[q*4] = *(const float4*)&Bs[t0 + j][q*4];
                *(float4*)&Ct[q*4] = *(const float4*)&Cs[t0 + j][q*4];
            }
            float yv = 0.f;
#pragma unroll
            for (int s = 0; s < 16; ++s) {
                float dA = __expf(dtv * A[s]);
                h[s] = dA * h[s] + dtu * Bt[s];
                yv += h[s] * Ct[s];
            }
            int m = mbase + t0 + j;
            yb[(size_t)m * DINNER + d] = f2bf((yv + uv * Dval) * szv);
        }
    }
}

// ---------------------------------------------------------------------------
// Final LayerNorm over DMODEL=512, reading bf16 h.
__global__ __launch_bounds__(256) void ln_kernel(
    const u16* __restrict__ hb, const float* __restrict__ g,
    const float* __restrict__ bta, float* __restrict__ out)
{
    int m = blockIdx.x;
    size_t base = (size_t)m * DMODEL;
    int t = threadIdx.x;
    float v0 = bf2f(hb[base + t]);
    float v1 = bf2f(hb[base + t + 256]);
    float sum = v0 + v1, sq = v0*v0 + v1*v1;
#pragma unroll
    for (int off = 32; off; off >>= 1) {
        sum += __shfl_down(sum, off);
        sq  += __shfl_down(sq,  off);
    }
    __shared__ float ls[4], lq[4];
    int w = t >> 6;
    if ((t & 63) == 0) { ls[w] = sum; lq[w] = sq; }
    __syncthreads();
    sum = ls[0] + ls[1] + ls[2] + ls[3];
    sq  = lq[0] + lq[1] + lq[2] + lq[3];
    float mu  = sum * (1.f / DMODEL);
    float var = sq * (1.f / DMODEL) - mu * mu;
    float rs  = rsqrtf(var + 1e-5f);
    out[base + t]       = (v0 - mu) * rs * g[t]       + bta[t];
    out[base + t + 256] = (v1 - mu) * rs * g[t + 256] + bta[t + 256];
}

// ---------------------------------------------------------------------------
extern "C" void kernel_launch(void* const* d_in, const int* in_sizes, int n_in,
                              void* d_out, int out_size, void* d_ws, size_t ws_size,
                              hipStream_t stream)
{
    const float* x      = (const float*)d_in[0];
    const float* in_w   = (const float*)d_in[1];
    const float* in_b   = (const float*)d_in[2];
    const float* W_xz   = (const float*)d_in[3];
    const float* conv_w = (const float*)d_in[4];
    const float* conv_b = (const float*)d_in[5];
    const float* W_xp   = (const float*)d_in[6];
    const float* W_dt   = (const float*)d_in[7];
    const float* b_dt   = (const float*)d_in[8];
    const float* A_log  = (const float*)d_in[9];
    const float* D_par  = (const float*)d_in[10];
    const float* W_out  = (const float*)d_in[11];
    const float* ln_g   = (const float*)d_in[12];
    const float* ln_b   = (const float*)d_in[13];
    float* out = (float*)d_out;

    // Workspace layout (floats), total ~19 M floats = 76 MB.
    float* ws      = (float*)d_ws;
    float* hbF     = ws;                    // 1 M   : hb bf16 (2M u16)
    float* hfinF   = hbF    + 1048576;      // 2 M   : hfinal bf16 (4M u16)
    float* xcbF    = hfinF  + 2097152;      // 2 M   : xc bf16
    float* szbF    = xcbF   + 2097152;      // 2 M   : silu(z) bf16
    float* ubF     = szbF   + 2097152;      // 2 M   : u bf16
    float* xdbl    = ubF    + 2097152;      // 256 K : fp32 (B/C in cols 32..63)
    float* dtbF    = xdbl   + 262144;       // 2 M   : dt bf16
    float* ybF     = dtbF   + 2097152;      // 2 M   : y bf16
    float* wxzF    = ybF    + 2097152;      // 2 M   : Wxz bf16, all layers
    float* woutF   = wxzF   + 2097152;      // 1 M   : Wout bf16, all layers
    float* wxpF    = woutF  + 1048576;      // 128 K : Wxp bf16, all layers
    float* wdtF    = wxpF   + 131072;       // 64 K  : Wdt bf16, all layers
    float* dsum    = wdtF   + 65536;        // 256 K : per-chunk dt sums fp32
    float* xpart   = dsum   + 262144;       // 2 M   : xp K-split partials fp32

    u16* hb     = (u16*)hbF;
    u16* hfinal = (u16*)hfinF;
    u16* xcb  = (u16*)xcbF;
    u16* szb  = (u16*)szbF;
    u16* ub   = (u16*)ubF;
    u16* dtb  = (u16*)dtbF;
    u16* yb   = (u16*)ybF;
    u16* wxzb  = (u16*)wxzF;
    u16* woutb = (u16*)woutF;
    u16* wxpb  = (u16*)wxpF;
    u16* wdtb  = (u16*)wdtF;

    // One-time weight prep (single dispatch).
    wprep_kernel<<<3264, 256, 0, stream>>>(W_xz, W_out, W_xp, W_dt,
                                           wxzb, woutb, wxpb, wdtb);

    in_proj_kernel<<<MTOT*DMODEL/256, 256, 0, stream>>>(x, in_w, in_b, hb);

    for (int layer = 0; layer < DEPTH_; ++layer) {
        const float* cw    = conv_w + (size_t)layer * DINNER * DCONV;
        const float* cb    = conv_b + (size_t)layer * DINNER;
        const float* bdt   = b_dt   + (size_t)layer * DINNER;
        const float* Alog  = A_log  + (size_t)layer * DINNER * DSTATE;
        const float* Dp    = D_par  + (size_t)layer * DINNER;
        const u16* wxzL    = wxzb  + (size_t)layer * 2048 * DMODEL;
        const u16* woutL   = woutb + (size_t)layer * DMODEL * DINNER;
        const u16* wxpL    = wxpb  + (size_t)layer * 64 * DINNER;
        const u16* wdtL    = wdtb  + (size_t)layer * DINNER * DTRANK;

        // xz GEMM (K=512), fused epilogue: bf16 xc + bf16 silu(z)
        gemm_bf16<128,128,1><<<dim3(2048/128, MTOT/128), 256, 0, stream>>>(
            hb, DMODEL, wxzL, DMODEL, xcb, szb, 0, DMODEL);
        // fused conv+silu+xp K-split GEMM (writes ub + xpart)
        xp_conv_kernel<<<dim3(XPSPLIT, MTOT/64), 256, 0, stream>>>(
            xcb, cw, cb, wxpL, ub, xpart);
        // fused xpred + dt GEMM (writes dtb + xdbl B/C)
        dt_fused_kernel<<<dim3(DINNER/64, MTOT/64), 256, 0, stream>>>(
            xpart, wdtL, bdt, dtb, xdbl);
        // chunked selective scan (bf16 chunk states)
        scan1_kernel<<<B_*CHUNKS*(DINNER/256), 256, 0, stream>>>(ub, xdbl, dtb, Alog, hfinal, dsum);
        scan2_kernel<<<(B_*DINNER*DSTATE)/256, 256, 0, stream>>>(hfinal, dsum, Alog);
        scan3_kernel<<<B_*CHUNKS*(DINNER/256), 256, 0, stream>>>(szb, ub, xdbl, dtb, Alog, Dp, hfinal, yb);
        // h = y @ Wout^T (K=1024), 64x64 tile, direct bf16 epilogue
        gemm_bf16<64,64,2><<<dim3(DMODEL/64, MTOT/64), 256, 0, stream>>>(
            yb, DINNER, woutL, DINNER, hb, nullptr, DMODEL, DINNER);
    }

    ln_kernel<<<MTOT, 256, 0, stream>>>(hb, ln_g, ln_b, out);
}

// Round 14
// 525.049 us; speedup vs baseline: 1.6648x; 1.0503x over previous
//
#include <hip/hip_runtime.h>
#include <math.h>

// Problem constants (match reference)
#define B_      4
#define L_      1024
#define D_INNC  8      // D_IN
#define DMODEL  512
#define DEPTH_  4
#define DINNER  1024
#define DSTATE  16
#define DCONV   4
#define DTRANK  32
#define MTOT    (B_*L_)   // 4096
#define CHUNKS  64
#define CLEN    16        // L_/CHUNKS
#define XPSPLIT 8         // xp GEMM K-splits (K=1024 -> 8 x 128)

typedef float f32x4 __attribute__((ext_vector_type(4)));
typedef short s16x8 __attribute__((ext_vector_type(8)));
typedef unsigned short u16;
typedef unsigned short u16x4v __attribute__((ext_vector_type(4)));

#define GLOBAL_AS __attribute__((address_space(1)))
#define LDS_AS    __attribute__((address_space(3)))

// fp32 -> bf16 round-to-nearest-even
__device__ __forceinline__ u16 f2bf(float v) {
    unsigned b = __float_as_uint(v);
    return (u16)((b + 0x7FFF + ((b >> 16) & 1)) >> 16);
}
__device__ __forceinline__ float bf2f(u16 h) {
    return __uint_as_float((unsigned)h << 16);
}

// ---------------------------------------------------------------------------
// h = x @ in_w^T + in_b  -> bf16 (4096 x 512, K=8)
__global__ __launch_bounds__(256) void in_proj_kernel(
    const float* __restrict__ x, const float* __restrict__ w,
    const float* __restrict__ bias, u16* __restrict__ hb)
{
    int idx = blockIdx.x * 256 + threadIdx.x;
    int m = idx / DMODEL, d = idx % DMODEL;
    const float* xr = x + m * D_INNC;
    const float* wr = w + d * D_INNC;
    float acc = bias[d];
#pragma unroll
    for (int k = 0; k < D_INNC; ++k) acc += xr[k] * wr[k];
    hb[idx] = f2bf(acc);
}

// ---------------------------------------------------------------------------
// One-shot fp32 -> bf16 convert of ALL four GEMM weight arrays.
// Boundaries (in 8-elem units): Wxz 524288 | Wout 262144 | Wxp 32768 | Wdt 16384.
__global__ __launch_bounds__(256) void wprep_kernel(
    const float* __restrict__ Wxz, const float* __restrict__ Wout,
    const float* __restrict__ Wxp, const float* __restrict__ Wdt,
    u16* __restrict__ wxzb, u16* __restrict__ woutb,
    u16* __restrict__ wxpb, u16* __restrict__ wdtb)
{
    int i = blockIdx.x * 256 + threadIdx.x;     // 0 .. 835583
    const float* src; u16* dst; int off;
    if (i < 524288)      { src = Wxz;  dst = wxzb;  off = i; }
    else if (i < 786432) { src = Wout; dst = woutb; off = i - 524288; }
    else if (i < 819200) { src = Wxp;  dst = wxpb;  off = i - 786432; }
    else                 { src = Wdt;  dst = wdtb;  off = i - 819200; }
    const float* s = src + (size_t)off * 8;
    float4 f0 = *(const float4*)s;
    float4 f1 = *(const float4*)(s + 4);
    float f[8] = {f0.x,f0.y,f0.z,f0.w,f1.x,f1.y,f1.z,f1.w};
    s16x8 hv;
#pragma unroll
    for (int e = 0; e < 8; ++e) hv[e] = (short)f2bf(f[e]);
    *(s16x8*)(dst + (size_t)off * 8) = hv;
}

// ---------------------------------------------------------------------------
// Async-stage one ROWS x 32(u16) K-slice into linear LDS [ROWS][32] via
// global_load_lds width=16. Slot permutation applied on the GLOBAL source
// (linear dest + inverse-swizzled source + swizzled read).
template<int ROWS>
__device__ __forceinline__ void stage_tile(
    const u16* __restrict__ src, int ld, int koff, u16* lds, int t)
{
    const int l = t & 63, w = t >> 6;
    const int r_in = l >> 2, s = l & 3;
#pragma unroll
    for (int p = 0; p < ROWS / 64; ++p) {
        int rb = (p * 4 + w) * 16;            // wave-uniform row base
        int r  = rb + r_in;
        int sw = s ^ ((r ^ (r >> 2)) & 3);    // pre-swizzled source slot
        const u16* g = src + (size_t)r * ld + koff + sw * 8;
        u16* lp = lds + rb * 32;              // uniform per wave
        __builtin_amdgcn_global_load_lds(
            (const GLOBAL_AS void*)g, (LDS_AS void*)lp, 16, 0, 0);
    }
}

// ---------------------------------------------------------------------------
// bf16 MFMA NT GEMM (standalone): swapped-operand mfma(b,a), packed stores.
// MODE 1: xz epilogue — col<1024: bf16 xcb; col>=1024: silu -> bf16 szb.
// MODE 2: bf16 direct out to C0 (ldc).
template<int BM, int BN, int MODE>
__global__ __launch_bounds__(256, 2) void gemm_bf16(
    const u16* __restrict__ A, int lda,
    const u16* __restrict__ B, int ldb,
    void* __restrict__ C0, void* __restrict__ C1,
    int ldc, int K)
{
    constexpr int FM = BM / 32;
    constexpr int FN = BN / 32;
    __shared__ __align__(16) u16 As[2][BM * 32];
    __shared__ __align__(16) u16 Bs[2][BN * 32];

    const int t    = threadIdx.x;
    const int lane = t & 63;
    const int w    = t >> 6;
    const int wm   = (w >> 1) * (BM / 2);
    const int wn   = (w & 1) * (BN / 2);
    const int quad = lane >> 4;
    const int l16  = lane & 15;
    const int m0   = blockIdx.y * BM;
    const int n0   = blockIdx.x * BN;
    const int sq   = (quad ^ ((l16 ^ (l16 >> 2)) & 3)) * 8;

    const u16* Abase = A + (size_t)m0 * lda;
    const u16* Bbase = B + (size_t)n0 * ldb;

    f32x4 acc[FM][FN];
#pragma unroll
    for (int i = 0; i < FM; ++i)
#pragma unroll
        for (int j = 0; j < FN; ++j) acc[i][j] = (f32x4){0.f,0.f,0.f,0.f};

    stage_tile<BM>(Abase, lda, 0, As[0], t);
    stage_tile<BN>(Bbase, ldb, 0, Bs[0], t);

    int cur = 0;
    for (int kk = 0; kk < K; kk += 32) {
        __syncthreads();                    // drains vmcnt: buf[cur] ready
        int kn = kk + 32;
        if (kn < K) {
            stage_tile<BM>(Abase, lda, kn, As[cur ^ 1], t);
            stage_tile<BN>(Bbase, ldb, kn, Bs[cur ^ 1], t);
        }
        s16x8 afr[FM], bfr[FN];
#pragma unroll
        for (int i = 0; i < FM; ++i) {
            int row = wm + i * 16 + l16;
            afr[i] = *(const s16x8*)&As[cur][row * 32 + sq];
        }
#pragma unroll
        for (int j = 0; j < FN; ++j) {
            int row = wn + j * 16 + l16;
            bfr[j] = *(const s16x8*)&Bs[cur][row * 32 + sq];
        }
#pragma unroll
        for (int i = 0; i < FM; ++i)
#pragma unroll
            for (int j = 0; j < FN; ++j)
                acc[i][j] = __builtin_amdgcn_mfma_f32_16x16x32_bf16(bfr[j], afr[i], acc[i][j], 0, 0, 0);
        cur ^= 1;
    }

    if constexpr (MODE == 2) {
        u16* C = (u16*)C0;
#pragma unroll
        for (int i = 0; i < FM; ++i) {
            int m = m0 + wm + i*16 + l16;
#pragma unroll
            for (int j = 0; j < FN; ++j) {
                int nb = n0 + wn + j*16 + quad*4;
                u16x4v o;
#pragma unroll
                for (int r = 0; r < 4; ++r) o[r] = f2bf(acc[i][j][r]);
                *(u16x4v*)&C[(size_t)m * ldc + nb] = o;
            }
        }
    } else {    // MODE 1
        u16* xcb = (u16*)C0;
        u16* szb = (u16*)C1;
#pragma unroll
        for (int i = 0; i < FM; ++i) {
            int m = m0 + wm + i*16 + l16;
#pragma unroll
            for (int j = 0; j < FN; ++j) {
                int nb = n0 + wn + j*16 + quad*4;
                bool isz = nb >= DINNER;
                int cc = nb & (DINNER - 1);
                u16* dst = isz ? szb : xcb;
                u16x4v o;
#pragma unroll
                for (int r = 0; r < 4; ++r) {
                    float v = acc[i][j][r];
                    if (isz) v = v / (1.f + __expf(-v));   // silu(z)
                    o[r] = f2bf(v);
                }
                *(u16x4v*)&dst[(size_t)m * DINNER + cc] = o;
            }
        }
    }
}

// ---------------------------------------------------------------------------
// Fused conv+silu+xp GEMM. Grid (XPSPLIT, MTOT/64). Split p, m-tile by.
// cw/cb for this split's 128 channels staged in LDS once.
__global__ __launch_bounds__(256) void xp_conv_kernel(
    const u16* __restrict__ xcb, const float* __restrict__ cw,
    const float* __restrict__ cb, const u16* __restrict__ wxpL,
    u16* __restrict__ ub, float* __restrict__ xpart)
{
    __shared__ __align__(16) u16 As[64 * 32];
    __shared__ __align__(16) u16 Bs[64 * 32];
    __shared__ __align__(16) float cws[512];   // cw[kbase..kbase+128)[4]
    __shared__ __align__(16) float cbs[128];   // cb[kbase..kbase+128)

    const int t    = threadIdx.x;
    const int lane = t & 63;
    const int w    = t >> 6;
    const int wm   = (w >> 1) * 32;
    const int wn   = (w & 1) * 32;
    const int quad = lane >> 4;
    const int l16  = lane & 15;
    const int p    = blockIdx.x;
    const int m0   = blockIdx.y * 64;
    const int kbase= p * 128;
    const int sq   = (quad ^ ((l16 ^ (l16 >> 2)) & 3)) * 8;

    const int r_st   = t >> 2;
    const int slot   = t & 3;
    const int m_st   = m0 + r_st;
    const int l_st   = m_st & (L_ - 1);
    const int swz    = slot ^ ((r_st ^ (r_st >> 2)) & 3);

    if (t < 128) *(float4*)&cws[t*4] = *(const float4*)&cw[(size_t)kbase*4 + t*4];
    if (t >= 128 && t < 160) {
        int i = t - 128;
        *(float4*)&cbs[i*4] = *(const float4*)&cb[kbase + i*4];
    }

    f32x4 acc[2][2];
#pragma unroll
    for (int i = 0; i < 2; ++i)
#pragma unroll
        for (int j = 0; j < 2; ++j) acc[i][j] = (f32x4){0.f,0.f,0.f,0.f};

    for (int ks = 0; ks < 4; ++ks) {
        const int kcol = kbase + ks * 32;
        const int dl0  = ks * 32 + slot * 8;    // tile-local channel base
        const int d0   = kcol + slot * 8;
        __syncthreads();        // LDS writable (and cws/cbs visible on ks=0)
        {   // ---- A-stage: u = silu(conv(xc)+cb) for 8 channels ----
            float a8[8];
#pragma unroll
            for (int e = 0; e < 8; ++e) a8[e] = cbs[dl0 + e];
#pragma unroll
            for (int k = 0; k < 4; ++k) {
                int lag = 3 - k;
                if (l_st >= lag) {
                    s16x8 xv = *(const s16x8*)&xcb[(size_t)(m_st - lag) * DINNER + d0];
#pragma unroll
                    for (int e = 0; e < 8; ++e)
                        a8[e] += bf2f((u16)xv[e]) * cws[(dl0 + e) * 4 + k];
                }
            }
            s16x8 hv;
#pragma unroll
            for (int e = 0; e < 8; ++e) {
                float v = a8[e];
                v = v / (1.f + __expf(-v));
                hv[e] = (short)f2bf(v);
            }
            *(s16x8*)&As[r_st * 32 + swz * 8] = hv;           // swizzled LDS
            *(s16x8*)&ub[(size_t)m_st * DINNER + d0] = hv;    // materialize u
        }
        stage_tile<64>(wxpL, DINNER, kcol, Bs, t);            // B async
        __syncthreads();        // ds_writes visible + vmcnt drained

        s16x8 afr[2], bfr[2];
#pragma unroll
        for (int i = 0; i < 2; ++i)
            afr[i] = *(const s16x8*)&As[(wm + i*16 + l16) * 32 + sq];
#pragma unroll
        for (int j = 0; j < 2; ++j)
            bfr[j] = *(const s16x8*)&Bs[(wn + j*16 + l16) * 32 + sq];
#pragma unroll
        for (int i = 0; i < 2; ++i)
#pragma unroll
            for (int j = 0; j < 2; ++j)
                acc[i][j] = __builtin_amdgcn_mfma_f32_16x16x32_bf16(bfr[j], afr[i], acc[i][j], 0, 0, 0);
    }

    float* P = xpart + (size_t)p * MTOT * 64;
#pragma unroll
    for (int i = 0; i < 2; ++i) {
        int m = m0 + wm + i*16 + l16;
#pragma unroll
        for (int j = 0; j < 2; ++j) {
            int nb = wn + j*16 + quad*4;
            float4 o;
            o.x = acc[i][j][0]; o.y = acc[i][j][1];
            o.z = acc[i][j][2]; o.w = acc[i][j][3];
            *(float4*)&P[(size_t)m * 64 + nb] = o;
        }
    }
}

// ---------------------------------------------------------------------------
// Fused xpred + dt GEMM. Grid (DINNER/64, MTOT/64) = (16, 64).
__global__ __launch_bounds__(256) void dt_fused_kernel(
    const float* __restrict__ xpart, const u16* __restrict__ wdtL,
    const float* __restrict__ bdt, u16* __restrict__ dtb,
    float* __restrict__ xdbl)
{
    __shared__ __align__(16) u16 As[64 * 32];
    __shared__ __align__(16) u16 Bs[64 * 32];

    const int t    = threadIdx.x;
    const int lane = t & 63;
    const int w    = t >> 6;
    const int wm   = (w >> 1) * 32;
    const int wn   = (w & 1) * 32;
    const int quad = lane >> 4;
    const int l16  = lane & 15;
    const int n0   = blockIdx.x * 64;
    const int m0   = blockIdx.y * 64;
    const int sq   = (quad ^ ((l16 ^ (l16 >> 2)) & 3)) * 8;

    const int r_st = t >> 2;
    const int slot = t & 3;
    const int swz  = slot ^ ((r_st ^ (r_st >> 2)) & 3);
    const int m_st = m0 + r_st;

    {   // ---- A-stage: dt_lr = bf16(sum partials cols 0..31) ----
        float s8[8];
#pragma unroll
        for (int e = 0; e < 8; ++e) s8[e] = 0.f;
#pragma unroll
        for (int p = 0; p < XPSPLIT; ++p) {
            const float* row = &xpart[((size_t)p * MTOT + m_st) * 64 + slot * 8];
            float4 v0 = *(const float4*)row;
            float4 v1 = *(const float4*)(row + 4);
#pragma unroll
            for (int e = 0; e < 4; ++e) { s8[e] += (&v0.x)[e]; s8[4+e] += (&v1.x)[e]; }
        }
        s16x8 hv;
#pragma unroll
        for (int e = 0; e < 8; ++e) hv[e] = (short)f2bf(s8[e]);
        *(s16x8*)&As[r_st * 32 + swz * 8] = hv;
    }
    stage_tile<64>(wdtL, DTRANK, 0, Bs, t);     // B async (64 x 32 bf16)
    if (blockIdx.x == 0) {  // ---- B/C fp32 sums (cols 32..63) -> xdbl ----
        const int c2 = 32 + slot * 8;
        float s8[8];
#pragma unroll
        for (int e = 0; e < 8; ++e) s8[e] = 0.f;
#pragma unroll
        for (int p = 0; p < XPSPLIT; ++p) {
            const float* row = &xpart[((size_t)p * MTOT + m_st) * 64 + c2];
            float4 v0 = *(const float4*)row;
            float4 v1 = *(const float4*)(row + 4);
#pragma unroll
            for (int e = 0; e < 4; ++e) { s8[e] += (&v0.x)[e]; s8[4+e] += (&v1.x)[e]; }
        }
        float4 o0, o1;
#pragma unroll
        for (int e = 0; e < 4; ++e) { (&o0.x)[e] = s8[e]; (&o1.x)[e] = s8[4+e]; }
        *(float4*)&xdbl[(size_t)m_st * 64 + c2]     = o0;
        *(float4*)&xdbl[(size_t)m_st * 64 + c2 + 4] = o1;
    }
    __syncthreads();

    f32x4 acc[2][2];
#pragma unroll
    for (int i = 0; i < 2; ++i)
#pragma unroll
        for (int j = 0; j < 2; ++j) acc[i][j] = (f32x4){0.f,0.f,0.f,0.f};

    s16x8 afr[2], bfr[2];
#pragma unroll
    for (int i = 0; i < 2; ++i)
        afr[i] = *(const s16x8*)&As[(wm + i*16 + l16) * 32 + sq];
#pragma unroll
    for (int j = 0; j < 2; ++j)
        bfr[j] = *(const s16x8*)&Bs[(wn + j*16 + l16) * 32 + sq];
#pragma unroll
    for (int i = 0; i < 2; ++i)
#pragma unroll
        for (int j = 0; j < 2; ++j)
            acc[i][j] = __builtin_amdgcn_mfma_f32_16x16x32_bf16(bfr[j], afr[i], acc[i][j], 0, 0, 0);

#pragma unroll
    for (int i = 0; i < 2; ++i) {
        int m = m0 + wm + i*16 + l16;
#pragma unroll
        for (int j = 0; j < 2; ++j) {
            int nb = n0 + wn + j*16 + quad*4;
            float4 bb4 = *(const float4*)&bdt[nb];
            u16x4v o;
#pragma unroll
            for (int r = 0; r < 4; ++r) {
                float v = acc[i][j][r] + (&bb4.x)[r];
                float sp = (v > 20.f) ? v : log1pf(__expf(v));
                o[r] = f2bf(sp);
            }
            *(u16x4v*)&dtb[(size_t)m * DINNER + nb] = o;
        }
    }
}

// ---------------------------------------------------------------------------
// Chunked scan pass 1 — LDS-staged u/dt tiles; geometric-exponent fast path:
// when A[s] == (s+1)*A[0] (reference A_log = log(1..16) broadcast),
// exp(dtv*A[s]) = e1^(s+1), e1 = exp(dtv*A[0]) — 1 exp + 15 muls per
// timestep instead of 16 exps (scans were v_exp-throughput bound).
__global__ __launch_bounds__(256) void scan1_kernel(
    const u16* __restrict__ ub, const float* xdbl,
    const u16* __restrict__ dtb, const float* __restrict__ A_log,
    u16* __restrict__ hfinal, float* __restrict__ dsum)
{
    __shared__ __align__(16) u16 Ut[CLEN][256];
    __shared__ __align__(16) u16 Dt[CLEN][256];
    __shared__ float Bs[CLEN][16];
    const int blk  = blockIdx.x;              // b*256 + c*4 + dblk
    const int dblk = blk & 3;
    const int c    = (blk >> 2) & (CHUNKS - 1);
    const int b    = blk >> 8;
    const int tid  = threadIdx.x;
    const int d    = dblk * 256 + tid;
    const int dbase= dblk * 256;
    const int mbase = b * L_ + c * CLEN;

#pragma unroll
    for (int q = 0; q < 2; ++q) {   // 16 rows x 256 cols, s16x8 per thread
        int i = (q * 256 + tid) * 8;
        int row = i >> 8, col = i & 255;
        *(s16x8*)&Ut[row][col] = *(const s16x8*)&ub [(size_t)(mbase + row) * DINNER + dbase + col];
        *(s16x8*)&Dt[row][col] = *(const s16x8*)&dtb[(size_t)(mbase + row) * DINNER + dbase + col];
    }
    {
        int tt = tid >> 4, ss = tid & 15;
        Bs[tt][ss] = xdbl[(size_t)(mbase + tt) * 64 + 32 + ss];
    }
    float A[16];
    {
        float4 a4[4];
#pragma unroll
        for (int q = 0; q < 4; ++q) a4[q] = *(const float4*)&A_log[d * 16 + q * 4];
        const float* af = (const float*)a4;
#pragma unroll
        for (int s = 0; s < 16; ++s) A[s] = -__expf(af[s]);
    }
    bool geo = true;
#pragma unroll
    for (int s = 1; s < 16; ++s)
        geo = geo && (fabsf(A[s] - (float)(s + 1) * A[0]) <= 1e-4f * (float)(s + 1));
    __syncthreads();

    float h[16];
#pragma unroll
    for (int s = 0; s < 16; ++s) h[s] = 0.f;
    float dts = 0.f;

    if (geo) {
        const float A0 = A[0];
        for (int t0 = 0; t0 < CLEN; t0 += 8) {
#pragma unroll
            for (int j = 0; j < 8; ++j) {
                float dtv = bf2f(Dt[t0 + j][tid]);
                float uv  = bf2f(Ut[t0 + j][tid]);
                float dtu = dtv * uv;
                dts += dtv;
                float Bt[16];
#pragma unroll
                for (int q = 0; q < 4; ++q)
                    *(float4*)&Bt[q*4] = *(const float4*)&Bs[t0 + j][q*4];
                float e1 = __expf(dtv * A0);
                float dA = e1;
#pragma unroll
                for (int s = 0; s < 16; ++s) {
                    h[s] = dA * h[s] + dtu * Bt[s];
                    dA *= e1;               // e1^(s+2) for next state
                }
            }
        }
    } else {
        for (int t0 = 0; t0 < CLEN; t0 += 8) {
#pragma unroll
            for (int j = 0; j < 8; ++j) {
                float dtv = bf2f(Dt[t0 + j][tid]);
                float uv  = bf2f(Ut[t0 + j][tid]);
                float dtu = dtv * uv;
                dts += dtv;
                float Bt[16];
#pragma unroll
                for (int q = 0; q < 4; ++q)
                    *(float4*)&Bt[q*4] = *(const float4*)&Bs[t0 + j][q*4];
#pragma unroll
                for (int s = 0; s < 16; ++s) {
                    float dA = __expf(dtv * A[s]);
                    h[s] = dA * h[s] + dtu * Bt[s];
                }
            }
        }
    }
    size_t base = ((size_t)(b * CHUNKS + c) * DINNER + d) * 16;
    s16x8 p0, p1;
#pragma unroll
    for (int s = 0; s < 8; ++s) { p0[s] = (short)f2bf(h[s]); p1[s] = (short)f2bf(h[s+8]); }
    *(s16x8*)&hfinal[base]     = p0;
    *(s16x8*)&hfinal[base + 8] = p1;
    dsum[(size_t)(b * CHUNKS + c) * DINNER + d] = dts;
}

// Pass 2: sequential chunk fix-up (bf16 states, fp32 math).
__global__ __launch_bounds__(256) void scan2_kernel(
    u16* __restrict__ hfinal, const float* __restrict__ dsum,
    const float* __restrict__ A_log)
{
    int t = blockIdx.x * 256 + threadIdx.x;   // 65536 = B_*DINNER*DSTATE
    int s = t & 15, d = (t >> 4) & (DINNER - 1), b = t >> 14;
    float As = -__expf(A_log[d * DSTATE + s]);
    float h = 0.f;
    for (int c0 = 0; c0 < CHUNKS; c0 += 8) {
        float hf8[8], dts8[8];
#pragma unroll
        for (int j = 0; j < 8; ++j) {
            int c = c0 + j;
            size_t i = (size_t)(b * CHUNKS + c) * DINNER + d;
            dts8[j] = dsum[i];
            hf8[j]  = bf2f(hfinal[i * 16 + s]);
        }
#pragma unroll
        for (int j = 0; j < 8; ++j) {
            int c = c0 + j;
            size_t idx = ((size_t)(b * CHUNKS + c) * DINNER + d) * 16 + s;
            hfinal[idx] = f2bf(h);
            h = __expf(As * dts8[j]) * h + hf8[j];
        }
    }
}

// Pass 3: seeded local scan; LDS-staged tiles + geometric-exponent fast path.
__global__ __launch_bounds__(256) void scan3_kernel(
    const u16* __restrict__ szb, const u16* __restrict__ ub,
    const float* xdbl, const u16* __restrict__ dtb,
    const float* __restrict__ A_log, const float* __restrict__ Dp,
    const u16* __restrict__ hstart, u16* __restrict__ yb)
{
    __shared__ __align__(16) u16 Ut[CLEN][256];
    __shared__ __align__(16) u16 Dt[CLEN][256];
    __shared__ __align__(16) u16 St[CLEN][256];
    __shared__ float Bs[CLEN][16];
    __shared__ float Cs[CLEN][16];
    const int blk  = blockIdx.x;
    const int dblk = blk & 3;
    const int c    = (blk >> 2) & (CHUNKS - 1);
    const int b    = blk >> 8;
    const int tid  = threadIdx.x;
    const int d    = dblk * 256 + tid;
    const int dbase= dblk * 256;
    const int mbase = b * L_ + c * CLEN;

#pragma unroll
    for (int q = 0; q < 2; ++q) {
        int i = (q * 256 + tid) * 8;
        int row = i >> 8, col = i & 255;
        *(s16x8*)&Ut[row][col] = *(const s16x8*)&ub [(size_t)(mbase + row) * DINNER + dbase + col];
        *(s16x8*)&Dt[row][col] = *(const s16x8*)&dtb[(size_t)(mbase + row) * DINNER + dbase + col];
        *(s16x8*)&St[row][col] = *(const s16x8*)&szb[(size_t)(mbase + row) * DINNER + dbase + col];
    }
    {
        int tt = tid >> 4, ss = tid & 15;
        Bs[tt][ss] = xdbl[(size_t)(mbase + tt) * 64 + 32 + ss];
        Cs[tt][ss] = xdbl[(size_t)(mbase + tt) * 64 + 48 + ss];
    }
    float A[16];
    {
        float4 a4[4];
#pragma unroll
        for (int q = 0; q < 4; ++q) a4[q] = *(const float4*)&A_log[d * 16 + q * 4];
        const float* af = (const float*)a4;
#pragma unroll
        for (int s = 0; s < 16; ++s) A[s] = -__expf(af[s]);
    }
    bool geo = true;
#pragma unroll
    for (int s = 1; s < 16; ++s)
        geo = geo && (fabsf(A[s] - (float)(s + 1) * A[0]) <= 1e-4f * (float)(s + 1));
    const float Dval = Dp[d];

    float h[16];
    {
        size_t base = ((size_t)(b * CHUNKS + c) * DINNER + d) * 16;
        s16x8 p0 = *(const s16x8*)&hstart[base];
        s16x8 p1 = *(const s16x8*)&hstart[base + 8];
#pragma unroll
        for (int s = 0; s < 8; ++s) { h[s] = bf2f((u16)p0[s]); h[s+8] = bf2f((u16)p1[s]); }
    }
    __syncthreads();

    if (geo) {
        const float A0 = A[0];
        for (int t0 = 0; t0 < CLEN; t0 += 8) {
#pragma unroll
            for (int j = 0; j < 8; ++j) {
                float dtv = bf2f(Dt[t0 + j][tid]);
                float uv  = bf2f(Ut[t0 + j][tid]);
                float szv = bf2f(St[t0 + j][tid]);
                float dtu = dtv * uv;
                float Bt[16], Ct[16];
#pragma unroll
                for (int q = 0; q < 4; ++q) {
                    *(float4*)&Bt[q*4] = *(const float4*)&Bs[t0 + j][q*4];
                    *(float4*)&Ct[q*4] = *(const float4*)&Cs[t0 + j][q*4];
                }
                float e1 = __expf(dtv * A0);
                float dA = e1;
                float yv = 0.f;
#pragma unroll
                for (int s = 0; s < 16; ++s) {
                    h[s] = dA * h[s] + dtu * Bt[s];
                    yv += h[s] * Ct[s];
                    dA *= e1;
                }
                int m = mbase + t0 + j;
                yb[(size_t)m * DINNER + d] = f2bf((yv + uv * Dval) * szv);
            }
        }
    } else {
        for (int t0 = 0; t0 < CLEN; t0 += 8) {
#pragma unroll
            for (int j = 0; j < 8; ++j) {
                float dtv = bf2f(Dt[t0 + j][tid]);
                float uv  = bf2f(Ut[t0 + j][tid]);
                float szv = bf2f(St[t0 + j][tid]);
                float dtu = dtv * uv;
                float Bt[16], Ct[16];
#pragma unroll
                for (int q = 0; q < 4; ++q) {
                    *(float4*)&Bt[q*4] = *(const float4*)&Bs[t0 + j][q*4];
                    *(float4*)&Ct[q*4] = *(const float4*)&Cs[t0 + j][q*4];
                }
                float yv = 0.f;
#pragma unroll
                for (int s = 0; s < 16; ++s) {
                    float dA = __expf(dtv * A[s]);
                    h[s] = dA * h[s] + dtu * Bt[s];
                    yv += h[s] * Ct[s];
                }
                int m = mbase + t0 + j;
                yb[(size_t)m * DINNER + d] = f2bf((yv + uv * Dval) * szv);
            }
        }
    }
}

// ---------------------------------------------------------------------------
// Final LayerNorm over DMODEL=512, reading bf16 h.
__global__ __launch_bounds__(256) void ln_kernel(
    const u16* __restrict__ hb, const float* __restrict__ g,
    const float* __restrict__ bta, float* __restrict__ out)
{
    int m = blockIdx.x;
    size_t base = (size_t)m * DMODEL;
    int t = threadIdx.x;
    float v0 = bf2f(hb[base + t]);
    float v1 = bf2f(hb[base + t + 256]);
    float sum = v0 + v1, sq = v0*v0 + v1*v1;
#pragma unroll
    for (int off = 32; off; off >>= 1) {
        sum += __shfl_down(sum, off);
        sq  += __shfl_down(sq,  off);
    }
    __shared__ float ls[4], lq[4];
    int w = t >> 6;
    if ((t & 63) == 0) { ls[w] = sum; lq[w] = sq; }
    __syncthreads();
    sum = ls[0] + ls[1] + ls[2] + ls[3];
    sq  = lq[0] + lq[1] + lq[2] + lq[3];
    float mu  = sum * (1.f / DMODEL);
    float var = sq * (1.f / DMODEL) - mu * mu;
    float rs  = rsqrtf(var + 1e-5f);
    out[base + t]       = (v0 - mu) * rs * g[t]       + bta[t];
    out[base + t + 256] = (v1 - mu) * rs * g[t + 256] + bta[t + 256];
}

// ---------------------------------------------------------------------------
extern "C" void kernel_launch(void* const* d_in, const int* in_sizes, int n_in,
                              void* d_out, int out_size, void* d_ws, size_t ws_size,
                              hipStream_t stream)
{
    const float* x      = (const float*)d_in[0];
    const float* in_w   = (const float*)d_in[1];
    const float* in_b   = (const float*)d_in[2];
    const float* W_xz   = (const float*)d_in[3];
    const float* conv_w = (const float*)d_in[4];
    const float* conv_b = (const float*)d_in[5];
    const float* W_xp   = (const float*)d_in[6];
    const float* W_dt   = (const float*)d_in[7];
    const float* b_dt   = (const float*)d_in[8];
    const float* A_log  = (const float*)d_in[9];
    const float* D_par  = (const float*)d_in[10];
    const float* W_out  = (const float*)d_in[11];
    const float* ln_g   = (const float*)d_in[12];
    const float* ln_b   = (const float*)d_in[13];
    float* out = (float*)d_out;

    // Workspace layout (floats), total ~19 M floats = 76 MB.
    float* ws      = (float*)d_ws;
    float* hbF     = ws;                    // 1 M   : hb bf16 (2M u16)
    float* hfinF   = hbF    + 1048576;      // 2 M   : hfinal bf16 (4M u16)
    float* xcbF    = hfinF  + 2097152;      // 2 M   : xc bf16
    float* szbF    = xcbF   + 2097152;      // 2 M   : silu(z) bf16
    float* ubF     = szbF   + 2097152;      // 2 M   : u bf16
    float* xdbl    = ubF    + 2097152;      // 256 K : fp32 (B/C in cols 32..63)
    float* dtbF    = xdbl   + 262144;       // 2 M   : dt bf16
    float* ybF     = dtbF   + 2097152;      // 2 M   : y bf16
    float* wxzF    = ybF    + 2097152;      // 2 M   : Wxz bf16, all layers
    float* woutF   = wxzF   + 2097152;      // 1 M   : Wout bf16, all layers
    float* wxpF    = woutF  + 1048576;      // 128 K : Wxp bf16, all layers
    float* wdtF    = wxpF   + 131072;       // 64 K  : Wdt bf16, all layers
    float* dsum    = wdtF   + 65536;        // 256 K : per-chunk dt sums fp32
    float* xpart   = dsum   + 262144;       // 2 M   : xp K-split partials fp32

    u16* hb     = (u16*)hbF;
    u16* hfinal = (u16*)hfinF;
    u16* xcb  = (u16*)xcbF;
    u16* szb  = (u16*)szbF;
    u16* ub   = (u16*)ubF;
    u16* dtb  = (u16*)dtbF;
    u16* yb   = (u16*)ybF;
    u16* wxzb  = (u16*)wxzF;
    u16* woutb = (u16*)woutF;
    u16* wxpb  = (u16*)wxpF;
    u16* wdtb  = (u16*)wdtF;

    // One-time weight prep (single dispatch).
    wprep_kernel<<<3264, 256, 0, stream>>>(W_xz, W_out, W_xp, W_dt,
                                           wxzb, woutb, wxpb, wdtb);

    in_proj_kernel<<<MTOT*DMODEL/256, 256, 0, stream>>>(x, in_w, in_b, hb);

    for (int layer = 0; layer < DEPTH_; ++layer) {
        const float* cw    = conv_w + (size_t)layer * DINNER * DCONV;
        const float* cb    = conv_b + (size_t)layer * DINNER;
        const float* bdt   = b_dt   + (size_t)layer * DINNER;
        const float* Alog  = A_log  + (size_t)layer * DINNER * DSTATE;
        const float* Dp    = D_par  + (size_t)layer * DINNER;
        const u16* wxzL    = wxzb  + (size_t)layer * 2048 * DMODEL;
        const u16* woutL   = woutb + (size_t)layer * DMODEL * DINNER;
        const u16* wxpL    = wxpb  + (size_t)layer * 64 * DINNER;
        const u16* wdtL    = wdtb  + (size_t)layer * DINNER * DTRANK;

        // xz GEMM (K=512), fused epilogue: bf16 xc + bf16 silu(z)
        gemm_bf16<128,128,1><<<dim3(2048/128, MTOT/128), 256, 0, stream>>>(
            hb, DMODEL, wxzL, DMODEL, xcb, szb, 0, DMODEL);
        // fused conv+silu+xp K-split GEMM (writes ub + xpart)
        xp_conv_kernel<<<dim3(XPSPLIT, MTOT/64), 256, 0, stream>>>(
            xcb, cw, cb, wxpL, ub, xpart);
        // fused xpred + dt GEMM (writes dtb + xdbl B/C)
        dt_fused_kernel<<<dim3(DINNER/64, MTOT/64), 256, 0, stream>>>(
            xpart, wdtL, bdt, dtb, xdbl);
        // chunked selective scan (bf16 chunk states)
        scan1_kernel<<<B_*CHUNKS*(DINNER/256), 256, 0, stream>>>(ub, xdbl, dtb, Alog, hfinal, dsum);
        scan2_kernel<<<(B_*DINNER*DSTATE)/256, 256, 0, stream>>>(hfinal, dsum, Alog);
        scan3_kernel<<<B_*CHUNKS*(DINNER/256), 256, 0, stream>>>(szb, ub, xdbl, dtb, Alog, Dp, hfinal, yb);
        // h = y @ Wout^T (K=1024), 64x64 tile, direct bf16 epilogue
        gemm_bf16<64,64,2><<<dim3(DMODEL/64, MTOT/64), 256, 0, stream>>>(
            yb, DINNER, woutL, DINNER, hb, nullptr, DMODEL, DINNER);
    }

    ln_kernel<<<MTOT, 256, 0, stream>>>(hb, ln_g, ln_b, out);
}

// Round 15
// 517.212 us; speedup vs baseline: 1.6900x; 1.0152x over previous
//
#include <hip/hip_runtime.h>
#include <math.h>

// Problem constants (match reference)
#define B_      4
#define L_      1024
#define D_INNC  8      // D_IN
#define DMODEL  512
#define DEPTH_  4
#define DINNER  1024
#define DSTATE  16
#define DCONV   4
#define DTRANK  32
#define MTOT    (B_*L_)   // 4096
#define CHUNKS  64
#define CLEN    16        // L_/CHUNKS
#define XPSPLIT 8         // xp GEMM K-splits (K=1024 -> 8 x 128)

typedef float f32x4 __attribute__((ext_vector_type(4)));
typedef short s16x8 __attribute__((ext_vector_type(8)));
typedef unsigned short u16;
typedef unsigned short u16x4v __attribute__((ext_vector_type(4)));

#define GLOBAL_AS __attribute__((address_space(1)))
#define LDS_AS    __attribute__((address_space(3)))

// fp32 -> bf16 round-to-nearest-even
__device__ __forceinline__ u16 f2bf(float v) {
    unsigned b = __float_as_uint(v);
    return (u16)((b + 0x7FFF + ((b >> 16) & 1)) >> 16);
}
__device__ __forceinline__ float bf2f(u16 h) {
    return __uint_as_float((unsigned)h << 16);
}

// ---------------------------------------------------------------------------
// h = x @ in_w^T + in_b  -> bf16 (4096 x 512, K=8)
__global__ __launch_bounds__(256) void in_proj_kernel(
    const float* __restrict__ x, const float* __restrict__ w,
    const float* __restrict__ bias, u16* __restrict__ hb)
{
    int idx = blockIdx.x * 256 + threadIdx.x;
    int m = idx / DMODEL, d = idx % DMODEL;
    const float* xr = x + m * D_INNC;
    const float* wr = w + d * D_INNC;
    float acc = bias[d];
#pragma unroll
    for (int k = 0; k < D_INNC; ++k) acc += xr[k] * wr[k];
    hb[idx] = f2bf(acc);
}

// ---------------------------------------------------------------------------
// One-shot fp32 -> bf16 convert of ALL four GEMM weight arrays.
// Boundaries (in 8-elem units): Wxz 524288 | Wout 262144 | Wxp 32768 | Wdt 16384.
__global__ __launch_bounds__(256) void wprep_kernel(
    const float* __restrict__ Wxz, const float* __restrict__ Wout,
    const float* __restrict__ Wxp, const float* __restrict__ Wdt,
    u16* __restrict__ wxzb, u16* __restrict__ woutb,
    u16* __restrict__ wxpb, u16* __restrict__ wdtb)
{
    int i = blockIdx.x * 256 + threadIdx.x;     // 0 .. 835583
    const float* src; u16* dst; int off;
    if (i < 524288)      { src = Wxz;  dst = wxzb;  off = i; }
    else if (i < 786432) { src = Wout; dst = woutb; off = i - 524288; }
    else if (i < 819200) { src = Wxp;  dst = wxpb;  off = i - 786432; }
    else                 { src = Wdt;  dst = wdtb;  off = i - 819200; }
    const float* s = src + (size_t)off * 8;
    float4 f0 = *(const float4*)s;
    float4 f1 = *(const float4*)(s + 4);
    float f[8] = {f0.x,f0.y,f0.z,f0.w,f1.x,f1.y,f1.z,f1.w};
    s16x8 hv;
#pragma unroll
    for (int e = 0; e < 8; ++e) hv[e] = (short)f2bf(f[e]);
    *(s16x8*)(dst + (size_t)off * 8) = hv;
}

// ---------------------------------------------------------------------------
// Async-stage one ROWS x 32(u16) K-slice into linear LDS [ROWS][32] via
// global_load_lds width=16. Slot permutation applied on the GLOBAL source
// (linear dest + inverse-swizzled source + swizzled read).
template<int ROWS>
__device__ __forceinline__ void stage_tile(
    const u16* __restrict__ src, int ld, int koff, u16* lds, int t)
{
    const int l = t & 63, w = t >> 6;
    const int r_in = l >> 2, s = l & 3;
#pragma unroll
    for (int p = 0; p < ROWS / 64; ++p) {
        int rb = (p * 4 + w) * 16;            // wave-uniform row base
        int r  = rb + r_in;
        int sw = s ^ ((r ^ (r >> 2)) & 3);    // pre-swizzled source slot
        const u16* g = src + (size_t)r * ld + koff + sw * 8;
        u16* lp = lds + rb * 32;              // uniform per wave
        __builtin_amdgcn_global_load_lds(
            (const GLOBAL_AS void*)g, (LDS_AS void*)lp, 16, 0, 0);
    }
}

// ---------------------------------------------------------------------------
// bf16 MFMA NT GEMM (standalone): swapped-operand mfma(b,a), packed stores.
// MODE 1: xz epilogue — col<1024: bf16 xcb; col>=1024: silu -> bf16 szb.
// MODE 2: bf16 direct out to C0 (ldc).
template<int BM, int BN, int MODE>
__global__ __launch_bounds__(256, 2) void gemm_bf16(
    const u16* __restrict__ A, int lda,
    const u16* __restrict__ B, int ldb,
    void* __restrict__ C0, void* __restrict__ C1,
    int ldc, int K)
{
    constexpr int FM = BM / 32;
    constexpr int FN = BN / 32;
    __shared__ __align__(16) u16 As[2][BM * 32];
    __shared__ __align__(16) u16 Bs[2][BN * 32];

    const int t    = threadIdx.x;
    const int lane = t & 63;
    const int w    = t >> 6;
    const int wm   = (w >> 1) * (BM / 2);
    const int wn   = (w & 1) * (BN / 2);
    const int quad = lane >> 4;
    const int l16  = lane & 15;
    const int m0   = blockIdx.y * BM;
    const int n0   = blockIdx.x * BN;
    const int sq   = (quad ^ ((l16 ^ (l16 >> 2)) & 3)) * 8;

    const u16* Abase = A + (size_t)m0 * lda;
    const u16* Bbase = B + (size_t)n0 * ldb;

    f32x4 acc[FM][FN];
#pragma unroll
    for (int i = 0; i < FM; ++i)
#pragma unroll
        for (int j = 0; j < FN; ++j) acc[i][j] = (f32x4){0.f,0.f,0.f,0.f};

    stage_tile<BM>(Abase, lda, 0, As[0], t);
    stage_tile<BN>(Bbase, ldb, 0, Bs[0], t);

    int cur = 0;
    for (int kk = 0; kk < K; kk += 32) {
        __syncthreads();                    // drains vmcnt: buf[cur] ready
        int kn = kk + 32;
        if (kn < K) {
            stage_tile<BM>(Abase, lda, kn, As[cur ^ 1], t);
            stage_tile<BN>(Bbase, ldb, kn, Bs[cur ^ 1], t);
        }
        s16x8 afr[FM], bfr[FN];
#pragma unroll
        for (int i = 0; i < FM; ++i) {
            int row = wm + i * 16 + l16;
            afr[i] = *(const s16x8*)&As[cur][row * 32 + sq];
        }
#pragma unroll
        for (int j = 0; j < FN; ++j) {
            int row = wn + j * 16 + l16;
            bfr[j] = *(const s16x8*)&Bs[cur][row * 32 + sq];
        }
#pragma unroll
        for (int i = 0; i < FM; ++i)
#pragma unroll
            for (int j = 0; j < FN; ++j)
                acc[i][j] = __builtin_amdgcn_mfma_f32_16x16x32_bf16(bfr[j], afr[i], acc[i][j], 0, 0, 0);
        cur ^= 1;
    }

    if constexpr (MODE == 2) {
        u16* C = (u16*)C0;
#pragma unroll
        for (int i = 0; i < FM; ++i) {
            int m = m0 + wm + i*16 + l16;
#pragma unroll
            for (int j = 0; j < FN; ++j) {
                int nb = n0 + wn + j*16 + quad*4;
                u16x4v o;
#pragma unroll
                for (int r = 0; r < 4; ++r) o[r] = f2bf(acc[i][j][r]);
                *(u16x4v*)&C[(size_t)m * ldc + nb] = o;
            }
        }
    } else {    // MODE 1
        u16* xcb = (u16*)C0;
        u16* szb = (u16*)C1;
#pragma unroll
        for (int i = 0; i < FM; ++i) {
            int m = m0 + wm + i*16 + l16;
#pragma unroll
            for (int j = 0; j < FN; ++j) {
                int nb = n0 + wn + j*16 + quad*4;
                bool isz = nb >= DINNER;
                int cc = nb & (DINNER - 1);
                u16* dst = isz ? szb : xcb;
                u16x4v o;
#pragma unroll
                for (int r = 0; r < 4; ++r) {
                    float v = acc[i][j][r];
                    if (isz) v = v / (1.f + __expf(-v));   // silu(z)
                    o[r] = f2bf(v);
                }
                *(u16x4v*)&dst[(size_t)m * DINNER + cc] = o;
            }
        }
    }
}

// ---------------------------------------------------------------------------
// Fused conv+silu+xp GEMM, 2-barrier schedule. Grid (XPSPLIT, MTOT/64).
// Barrier 1: cws/cbs visible. Then: issue all 4 async B stages, compute all
// 4 conv/silu groups (B HBM latency hides under conv VALU), barrier 2, then
// 16 MFMAs. Was 8 barriers (one vmcnt-drain pair per K-step).
__global__ __launch_bounds__(256) void xp_conv_kernel(
    const u16* __restrict__ xcb, const float* __restrict__ cw,
    const float* __restrict__ cb, const u16* __restrict__ wxpL,
    u16* __restrict__ ub, float* __restrict__ xpart)
{
    __shared__ __align__(16) u16 As[4][64 * 32];
    __shared__ __align__(16) u16 Bs[4][64 * 32];
    __shared__ __align__(16) float cws[512];   // cw[kbase..kbase+128)[4]
    __shared__ __align__(16) float cbs[128];   // cb[kbase..kbase+128)

    const int t    = threadIdx.x;
    const int lane = t & 63;
    const int w    = t >> 6;
    const int wm   = (w >> 1) * 32;
    const int wn   = (w & 1) * 32;
    const int quad = lane >> 4;
    const int l16  = lane & 15;
    const int p    = blockIdx.x;
    const int m0   = blockIdx.y * 64;
    const int kbase= p * 128;
    const int sq   = (quad ^ ((l16 ^ (l16 >> 2)) & 3)) * 8;

    const int r_st   = t >> 2;
    const int slot   = t & 3;
    const int m_st   = m0 + r_st;
    const int l_st   = m_st & (L_ - 1);
    const int swz    = slot ^ ((r_st ^ (r_st >> 2)) & 3);

    if (t < 128) *(float4*)&cws[t*4] = *(const float4*)&cw[(size_t)kbase*4 + t*4];
    if (t >= 128 && t < 160) {
        int i = t - 128;
        *(float4*)&cbs[i*4] = *(const float4*)&cb[kbase + i*4];
    }
    __syncthreads();                        // cws/cbs visible

    // Issue all B stages (async; drain at barrier 2, hidden under conv)
#pragma unroll
    for (int ks = 0; ks < 4; ++ks)
        stage_tile<64>(wxpL, DINNER, kbase + ks * 32, Bs[ks], t);

    // Conv+silu for all 4 channel groups -> As + ub
#pragma unroll
    for (int ks = 0; ks < 4; ++ks) {
        const int dl0 = ks * 32 + slot * 8;     // tile-local channel base
        const int d0  = kbase + dl0;
        float a8[8];
#pragma unroll
        for (int e = 0; e < 8; ++e) a8[e] = cbs[dl0 + e];
#pragma unroll
        for (int k = 0; k < 4; ++k) {
            int lag = 3 - k;
            if (l_st >= lag) {
                s16x8 xv = *(const s16x8*)&xcb[(size_t)(m_st - lag) * DINNER + d0];
#pragma unroll
                for (int e = 0; e < 8; ++e)
                    a8[e] += bf2f((u16)xv[e]) * cws[(dl0 + e) * 4 + k];
            }
        }
        s16x8 hv;
#pragma unroll
        for (int e = 0; e < 8; ++e) {
            float v = a8[e];
            v = v / (1.f + __expf(-v));
            hv[e] = (short)f2bf(v);
        }
        *(s16x8*)&As[ks][r_st * 32 + swz * 8] = hv;        // swizzled LDS
        *(s16x8*)&ub[(size_t)m_st * DINNER + d0] = hv;     // materialize u
    }
    __syncthreads();                        // As visible + B vmcnt drained

    f32x4 acc[2][2];
#pragma unroll
    for (int i = 0; i < 2; ++i)
#pragma unroll
        for (int j = 0; j < 2; ++j) acc[i][j] = (f32x4){0.f,0.f,0.f,0.f};

#pragma unroll
    for (int ks = 0; ks < 4; ++ks) {
        s16x8 afr[2], bfr[2];
#pragma unroll
        for (int i = 0; i < 2; ++i)
            afr[i] = *(const s16x8*)&As[ks][(wm + i*16 + l16) * 32 + sq];
#pragma unroll
        for (int j = 0; j < 2; ++j)
            bfr[j] = *(const s16x8*)&Bs[ks][(wn + j*16 + l16) * 32 + sq];
#pragma unroll
        for (int i = 0; i < 2; ++i)
#pragma unroll
            for (int j = 0; j < 2; ++j)
                acc[i][j] = __builtin_amdgcn_mfma_f32_16x16x32_bf16(bfr[j], afr[i], acc[i][j], 0, 0, 0);
    }

    float* P = xpart + (size_t)p * MTOT * 64;
#pragma unroll
    for (int i = 0; i < 2; ++i) {
        int m = m0 + wm + i*16 + l16;
#pragma unroll
        for (int j = 0; j < 2; ++j) {
            int nb = wn + j*16 + quad*4;
            float4 o;
            o.x = acc[i][j][0]; o.y = acc[i][j][1];
            o.z = acc[i][j][2]; o.w = acc[i][j][3];
            *(float4*)&P[(size_t)m * 64 + nb] = o;
        }
    }
}

// ---------------------------------------------------------------------------
// Fused xpred + dt GEMM. Grid (DINNER/64, MTOT/64) = (16, 64).
// FIX: B staging now offset by n0 (was staging Wdt rows 0..63 for all
// column-blocks since round 10).
__global__ __launch_bounds__(256) void dt_fused_kernel(
    const float* __restrict__ xpart, const u16* __restrict__ wdtL,
    const float* __restrict__ bdt, u16* __restrict__ dtb,
    float* __restrict__ xdbl)
{
    __shared__ __align__(16) u16 As[64 * 32];
    __shared__ __align__(16) u16 Bs[64 * 32];

    const int t    = threadIdx.x;
    const int lane = t & 63;
    const int w    = t >> 6;
    const int wm   = (w >> 1) * 32;
    const int wn   = (w & 1) * 32;
    const int quad = lane >> 4;
    const int l16  = lane & 15;
    const int n0   = blockIdx.x * 64;
    const int m0   = blockIdx.y * 64;
    const int sq   = (quad ^ ((l16 ^ (l16 >> 2)) & 3)) * 8;

    const int r_st = t >> 2;
    const int slot = t & 3;
    const int swz  = slot ^ ((r_st ^ (r_st >> 2)) & 3);
    const int m_st = m0 + r_st;

    // B async: Wdt rows n0..n0+63 (the rows this block's output columns use)
    stage_tile<64>(wdtL + (size_t)n0 * DTRANK, DTRANK, 0, Bs, t);

    {   // ---- A-stage: dt_lr = bf16(sum partials cols 0..31) ----
        float s8[8];
#pragma unroll
        for (int e = 0; e < 8; ++e) s8[e] = 0.f;
#pragma unroll
        for (int p = 0; p < XPSPLIT; ++p) {
            const float* row = &xpart[((size_t)p * MTOT + m_st) * 64 + slot * 8];
            float4 v0 = *(const float4*)row;
            float4 v1 = *(const float4*)(row + 4);
#pragma unroll
            for (int e = 0; e < 4; ++e) { s8[e] += (&v0.x)[e]; s8[4+e] += (&v1.x)[e]; }
        }
        s16x8 hv;
#pragma unroll
        for (int e = 0; e < 8; ++e) hv[e] = (short)f2bf(s8[e]);
        *(s16x8*)&As[r_st * 32 + swz * 8] = hv;
    }
    if (blockIdx.x == 0) {  // ---- B/C fp32 sums (cols 32..63) -> xdbl ----
        const int c2 = 32 + slot * 8;
        float s8[8];
#pragma unroll
        for (int e = 0; e < 8; ++e) s8[e] = 0.f;
#pragma unroll
        for (int p = 0; p < XPSPLIT; ++p) {
            const float* row = &xpart[((size_t)p * MTOT + m_st) * 64 + c2];
            float4 v0 = *(const float4*)row;
            float4 v1 = *(const float4*)(row + 4);
#pragma unroll
            for (int e = 0; e < 4; ++e) { s8[e] += (&v0.x)[e]; s8[4+e] += (&v1.x)[e]; }
        }
        float4 o0, o1;
#pragma unroll
        for (int e = 0; e < 4; ++e) { (&o0.x)[e] = s8[e]; (&o1.x)[e] = s8[4+e]; }
        *(float4*)&xdbl[(size_t)m_st * 64 + c2]     = o0;
        *(float4*)&xdbl[(size_t)m_st * 64 + c2 + 4] = o1;
    }
    __syncthreads();

    f32x4 acc[2][2];
#pragma unroll
    for (int i = 0; i < 2; ++i)
#pragma unroll
        for (int j = 0; j < 2; ++j) acc[i][j] = (f32x4){0.f,0.f,0.f,0.f};

    s16x8 afr[2], bfr[2];
#pragma unroll
    for (int i = 0; i < 2; ++i)
        afr[i] = *(const s16x8*)&As[(wm + i*16 + l16) * 32 + sq];
#pragma unroll
    for (int j = 0; j < 2; ++j)
        bfr[j] = *(const s16x8*)&Bs[(wn + j*16 + l16) * 32 + sq];
#pragma unroll
    for (int i = 0; i < 2; ++i)
#pragma unroll
        for (int j = 0; j < 2; ++j)
            acc[i][j] = __builtin_amdgcn_mfma_f32_16x16x32_bf16(bfr[j], afr[i], acc[i][j], 0, 0, 0);

#pragma unroll
    for (int i = 0; i < 2; ++i) {
        int m = m0 + wm + i*16 + l16;
#pragma unroll
        for (int j = 0; j < 2; ++j) {
            int nb = n0 + wn + j*16 + quad*4;
            float4 bb4 = *(const float4*)&bdt[nb];
            u16x4v o;
#pragma unroll
            for (int r = 0; r < 4; ++r) {
                float v = acc[i][j][r] + (&bb4.x)[r];
                float sp = (v > 20.f) ? v : log1pf(__expf(v));
                o[r] = f2bf(sp);
            }
            *(u16x4v*)&dtb[(size_t)m * DINNER + nb] = o;
        }
    }
}

// ---------------------------------------------------------------------------
// Chunked scan pass 1 — LDS-staged u/dt tiles; geometric-exponent fast path:
// when A[s] == (s+1)*A[0] (reference A_log = log(1..16) broadcast),
// exp(dtv*A[s]) = e1^(s+1), e1 = exp(dtv*A[0]) — 1 exp + 15 muls per
// timestep instead of 16 exps (scans were v_exp-throughput bound).
__global__ __launch_bounds__(256) void scan1_kernel(
    const u16* __restrict__ ub, const float* xdbl,
    const u16* __restrict__ dtb, const float* __restrict__ A_log,
    u16* __restrict__ hfinal, float* __restrict__ dsum)
{
    __shared__ __align__(16) u16 Ut[CLEN][256];
    __shared__ __align__(16) u16 Dt[CLEN][256];
    __shared__ float Bs[CLEN][16];
    const int blk  = blockIdx.x;              // b*256 + c*4 + dblk
    const int dblk = blk & 3;
    const int c    = (blk >> 2) & (CHUNKS - 1);
    const int b    = blk >> 8;
    const int tid  = threadIdx.x;
    const int d    = dblk * 256 + tid;
    const int dbase= dblk * 256;
    const int mbase = b * L_ + c * CLEN;

#pragma unroll
    for (int q = 0; q < 2; ++q) {   // 16 rows x 256 cols, s16x8 per thread
        int i = (q * 256 + tid) * 8;
        int row = i >> 8, col = i & 255;
        *(s16x8*)&Ut[row][col] = *(const s16x8*)&ub [(size_t)(mbase + row) * DINNER + dbase + col];
        *(s16x8*)&Dt[row][col] = *(const s16x8*)&dtb[(size_t)(mbase + row) * DINNER + dbase + col];
    }
    {
        int tt = tid >> 4, ss = tid & 15;
        Bs[tt][ss] = xdbl[(size_t)(mbase + tt) * 64 + 32 + ss];
    }
    float A[16];
    {
        float4 a4[4];
#pragma unroll
        for (int q = 0; q < 4; ++q) a4[q] = *(const float4*)&A_log[d * 16 + q * 4];
        const float* af = (const float*)a4;
#pragma unroll
        for (int s = 0; s < 16; ++s) A[s] = -__expf(af[s]);
    }
    bool geo = true;
#pragma unroll
    for (int s = 1; s < 16; ++s)
        geo = geo && (fabsf(A[s] - (float)(s + 1) * A[0]) <= 1e-4f * (float)(s + 1));
    __syncthreads();

    float h[16];
#pragma unroll
    for (int s = 0; s < 16; ++s) h[s] = 0.f;
    float dts = 0.f;

    if (geo) {
        const float A0 = A[0];
        for (int t0 = 0; t0 < CLEN; t0 += 8) {
#pragma unroll
            for (int j = 0; j < 8; ++j) {
                float dtv = bf2f(Dt[t0 + j][tid]);
                float uv  = bf2f(Ut[t0 + j][tid]);
                float dtu = dtv * uv;
                dts += dtv;
                float Bt[16];
#pragma unroll
                for (int q = 0; q < 4; ++q)
                    *(float4*)&Bt[q*4] = *(const float4*)&Bs[t0 + j][q*4];
                float e1 = __expf(dtv * A0);
                float dA = e1;
#pragma unroll
                for (int s = 0; s < 16; ++s) {
                    h[s] = dA * h[s] + dtu * Bt[s];
                    dA *= e1;               // e1^(s+2) for next state
                }
            }
        }
    } else {
        for (int t0 = 0; t0 < CLEN; t0 += 8) {
#pragma unroll
            for (int j = 0; j < 8; ++j) {
                float dtv = bf2f(Dt[t0 + j][tid]);
                float uv  = bf2f(Ut[t0 + j][tid]);
                float dtu = dtv * uv;
                dts += dtv;
                float Bt[16];
#pragma unroll
                for (int q = 0; q < 4; ++q)
                    *(float4*)&Bt[q*4] = *(const float4*)&Bs[t0 + j][q*4];
#pragma unroll
                for (int s = 0; s < 16; ++s) {
                    float dA = __expf(dtv * A[s]);
                    h[s] = dA * h[s] + dtu * Bt[s];
                }
            }
        }
    }
    size_t base = ((size_t)(b * CHUNKS + c) * DINNER + d) * 16;
    s16x8 p0, p1;
#pragma unroll
    for (int s = 0; s < 8; ++s) { p0[s] = (short)f2bf(h[s]); p1[s] = (short)f2bf(h[s+8]); }
    *(s16x8*)&hfinal[base]     = p0;
    *(s16x8*)&hfinal[base + 8] = p1;
    dsum[(size_t)(b * CHUNKS + c) * DINNER + d] = dts;
}

// Pass 2: sequential chunk fix-up (bf16 states, fp32 math).
__global__ __launch_bounds__(256) void scan2_kernel(
    u16* __restrict__ hfinal, const float* __restrict__ dsum,
    const float* __restrict__ A_log)
{
    int t = blockIdx.x * 256 + threadIdx.x;   // 65536 = B_*DINNER*DSTATE
    int s = t & 15, d = (t >> 4) & (DINNER - 1), b = t >> 14;
    float As = -__expf(A_log[d * DSTATE + s]);
    float h = 0.f;
    for (int c0 = 0; c0 < CHUNKS; c0 += 8) {
        float hf8[8], dts8[8];
#pragma unroll
        for (int j = 0; j < 8; ++j) {
            int c = c0 + j;
            size_t i = (size_t)(b * CHUNKS + c) * DINNER + d;
            dts8[j] = dsum[i];
            hf8[j]  = bf2f(hfinal[i * 16 + s]);
        }
#pragma unroll
        for (int j = 0; j < 8; ++j) {
            int c = c0 + j;
            size_t idx = ((size_t)(b * CHUNKS + c) * DINNER + d) * 16 + s;
            hfinal[idx] = f2bf(h);
            h = __expf(As * dts8[j]) * h + hf8[j];
        }
    }
}

// Pass 3: seeded local scan; LDS-staged tiles + geometric-exponent fast path.
__global__ __launch_bounds__(256) void scan3_kernel(
    const u16* __restrict__ szb, const u16* __restrict__ ub,
    const float* xdbl, const u16* __restrict__ dtb,
    const float* __restrict__ A_log, const float* __restrict__ Dp,
    const u16* __restrict__ hstart, u16* __restrict__ yb)
{
    __shared__ __align__(16) u16 Ut[CLEN][256];
    __shared__ __align__(16) u16 Dt[CLEN][256];
    __shared__ __align__(16) u16 St[CLEN][256];
    __shared__ float Bs[CLEN][16];
    __shared__ float Cs[CLEN][16];
    const int blk  = blockIdx.x;
    const int dblk = blk & 3;
    const int c    = (blk >> 2) & (CHUNKS - 1);
    const int b    = blk >> 8;
    const int tid  = threadIdx.x;
    const int d    = dblk * 256 + tid;
    const int dbase= dblk * 256;
    const int mbase = b * L_ + c * CLEN;

#pragma unroll
    for (int q = 0; q < 2; ++q) {
        int i = (q * 256 + tid) * 8;
        int row = i >> 8, col = i & 255;
        *(s16x8*)&Ut[row][col] = *(const s16x8*)&ub [(size_t)(mbase + row) * DINNER + dbase + col];
        *(s16x8*)&Dt[row][col] = *(const s16x8*)&dtb[(size_t)(mbase + row) * DINNER + dbase + col];
        *(s16x8*)&St[row][col] = *(const s16x8*)&szb[(size_t)(mbase + row) * DINNER + dbase + col];
    }
    {
        int tt = tid >> 4, ss = tid & 15;
        Bs[tt][ss] = xdbl[(size_t)(mbase + tt) * 64 + 32 + ss];
        Cs[tt][ss] = xdbl[(size_t)(mbase + tt) * 64 + 48 + ss];
    }
    float A[16];
    {
        float4 a4[4];
#pragma unroll
        for (int q = 0; q < 4; ++q) a4[q] = *(const float4*)&A_log[d * 16 + q * 4];
        const float* af = (const float*)a4;
#pragma unroll
        for (int s = 0; s < 16; ++s) A[s] = -__expf(af[s]);
    }
    bool geo = true;
#pragma unroll
    for (int s = 1; s < 16; ++s)
        geo = geo && (fabsf(A[s] - (float)(s + 1) * A[0]) <= 1e-4f * (float)(s + 1));
    const float Dval = Dp[d];

    float h[16];
    {
        size_t base = ((size_t)(b * CHUNKS + c) * DINNER + d) * 16;
        s16x8 p0 = *(const s16x8*)&hstart[base];
        s16x8 p1 = *(const s16x8*)&hstart[base + 8];
#pragma unroll
        for (int s = 0; s < 8; ++s) { h[s] = bf2f((u16)p0[s]); h[s+8] = bf2f((u16)p1[s]); }
    }
    __syncthreads();

    if (geo) {
        const float A0 = A[0];
        for (int t0 = 0; t0 < CLEN; t0 += 8) {
#pragma unroll
            for (int j = 0; j < 8; ++j) {
                float dtv = bf2f(Dt[t0 + j][tid]);
                float uv  = bf2f(Ut[t0 + j][tid]);
                float szv = bf2f(St[t0 + j][tid]);
                float dtu = dtv * uv;
                float Bt[16], Ct[16];
#pragma unroll
                for (int q = 0; q < 4; ++q) {
                    *(float4*)&Bt[q*4] = *(const float4*)&Bs[t0 + j][q*4];
                    *(float4*)&Ct[q*4] = *(const float4*)&Cs[t0 + j][q*4];
                }
                float e1 = __expf(dtv * A0);
                float dA = e1;
                float yv = 0.f;
#pragma unroll
                for (int s = 0; s < 16; ++s) {
                    h[s] = dA * h[s] + dtu * Bt[s];
                    yv += h[s] * Ct[s];
                    dA *= e1;
                }
                int m = mbase + t0 + j;
                yb[(size_t)m * DINNER + d] = f2bf((yv + uv * Dval) * szv);
            }
        }
    } else {
        for (int t0 = 0; t0 < CLEN; t0 += 8) {
#pragma unroll
            for (int j = 0; j < 8; ++j) {
                float dtv = bf2f(Dt[t0 + j][tid]);
                float uv  = bf2f(Ut[t0 + j][tid]);
                float szv = bf2f(St[t0 + j][tid]);
                float dtu = dtv * uv;
                float Bt[16], Ct[16];
#pragma unroll
                for (int q = 0; q < 4; ++q) {
                    *(float4*)&Bt[q*4] = *(const float4*)&Bs[t0 + j][q*4];
                    *(float4*)&Ct[q*4] = *(const float4*)&Cs[t0 + j][q*4];
                }
                float yv = 0.f;
#pragma unroll
                for (int s = 0; s < 16; ++s) {
                    float dA = __expf(dtv * A[s]);
                    h[s] = dA * h[s] + dtu * Bt[s];
                    yv += h[s] * Ct[s];
                }
                int m = mbase + t0 + j;
                yb[(size_t)m * DINNER + d] = f2bf((yv + uv * Dval) * szv);
            }
        }
    }
}

// ---------------------------------------------------------------------------
// Final LayerNorm over DMODEL=512, reading bf16 h.
__global__ __launch_bounds__(256) void ln_kernel(
    const u16* __restrict__ hb, const float* __restrict__ g,
    const float* __restrict__ bta, float* __restrict__ out)
{
    int m = blockIdx.x;
    size_t base = (size_t)m * DMODEL;
    int t = threadIdx.x;
    float v0 = bf2f(hb[base + t]);
    float v1 = bf2f(hb[base + t + 256]);
    float sum = v0 + v1, sq = v0*v0 + v1*v1;
#pragma unroll
    for (int off = 32; off; off >>= 1) {
        sum += __shfl_down(sum, off);
        sq  += __shfl_down(sq,  off);
    }
    __shared__ float ls[4], lq[4];
    int w = t >> 6;
    if ((t & 63) == 0) { ls[w] = sum; lq[w] = sq; }
    __syncthreads();
    sum = ls[0] + ls[1] + ls[2] + ls[3];
    sq  = lq[0] + lq[1] + lq[2] + lq[3];
    float mu  = sum * (1.f / DMODEL);
    float var = sq * (1.f / DMODEL) - mu * mu;
    float rs  = rsqrtf(var + 1e-5f);
    out[base + t]       = (v0 - mu) * rs * g[t]       + bta[t];
    out[base + t + 256] = (v1 - mu) * rs * g[t + 256] + bta[t + 256];
}

// ---------------------------------------------------------------------------
extern "C" void kernel_launch(void* const* d_in, const int* in_sizes, int n_in,
                              void* d_out, int out_size, void* d_ws, size_t ws_size,
                              hipStream_t stream)
{
    const float* x      = (const float*)d_in[0];
    const float* in_w   = (const float*)d_in[1];
    const float* in_b   = (const float*)d_in[2];
    const float* W_xz   = (const float*)d_in[3];
    const float* conv_w = (const float*)d_in[4];
    const float* conv_b = (const float*)d_in[5];
    const float* W_xp   = (const float*)d_in[6];
    const float* W_dt   = (const float*)d_in[7];
    const float* b_dt   = (const float*)d_in[8];
    const float* A_log  = (const float*)d_in[9];
    const float* D_par  = (const float*)d_in[10];
    const float* W_out  = (const float*)d_in[11];
    const float* ln_g   = (const float*)d_in[12];
    const float* ln_b   = (const float*)d_in[13];
    float* out = (float*)d_out;

    // Workspace layout (floats), total ~19 M floats = 76 MB.
    float* ws      = (float*)d_ws;
    float* hbF     = ws;                    // 1 M   : hb bf16 (2M u16)
    float* hfinF   = hbF    + 1048576;      // 2 M   : hfinal bf16 (4M u16)
    float* xcbF    = hfinF  + 2097152;      // 2 M   : xc bf16
    float* szbF    = xcbF   + 2097152;      // 2 M   : silu(z) bf16
    float* ubF     = szbF   + 2097152;      // 2 M   : u bf16
    float* xdbl    = ubF    + 2097152;      // 256 K : fp32 (B/C in cols 32..63)
    float* dtbF    = xdbl   + 262144;       // 2 M   : dt bf16
    float* ybF     = dtbF   + 2097152;      // 2 M   : y bf16
    float* wxzF    = ybF    + 2097152;      // 2 M   : Wxz bf16, all layers
    float* woutF   = wxzF   + 2097152;      // 1 M   : Wout bf16, all layers
    float* wxpF    = woutF  + 1048576;      // 128 K : Wxp bf16, all layers
    float* wdtF    = wxpF   + 131072;       // 64 K  : Wdt bf16, all layers
    float* dsum    = wdtF   + 65536;        // 256 K : per-chunk dt sums fp32
    float* xpart   = dsum   + 262144;       // 2 M   : xp K-split partials fp32

    u16* hb     = (u16*)hbF;
    u16* hfinal = (u16*)hfinF;
    u16* xcb  = (u16*)xcbF;
    u16* szb  = (u16*)szbF;
    u16* ub   = (u16*)ubF;
    u16* dtb  = (u16*)dtbF;
    u16* yb   = (u16*)ybF;
    u16* wxzb  = (u16*)wxzF;
    u16* woutb = (u16*)woutF;
    u16* wxpb  = (u16*)wxpF;
    u16* wdtb  = (u16*)wdtF;

    // One-time weight prep (single dispatch).
    wprep_kernel<<<3264, 256, 0, stream>>>(W_xz, W_out, W_xp, W_dt,
                                           wxzb, woutb, wxpb, wdtb);

    in_proj_kernel<<<MTOT*DMODEL/256, 256, 0, stream>>>(x, in_w, in_b, hb);

    for (int layer = 0; layer < DEPTH_; ++layer) {
        const float* cw    = conv_w + (size_t)layer * DINNER * DCONV;
        const float* cb    = conv_b + (size_t)layer * DINNER;
        const float* bdt   = b_dt   + (size_t)layer * DINNER;
        const float* Alog  = A_log  + (size_t)layer * DINNER * DSTATE;
        const float* Dp    = D_par  + (size_t)layer * DINNER;
        const u16* wxzL    = wxzb  + (size_t)layer * 2048 * DMODEL;
        const u16* woutL   = woutb + (size_t)layer * DMODEL * DINNER;
        const u16* wxpL    = wxpb  + (size_t)layer * 64 * DINNER;
        const u16* wdtL    = wdtb  + (size_t)layer * DINNER * DTRANK;

        // xz GEMM (K=512), fused epilogue: bf16 xc + bf16 silu(z)
        gemm_bf16<128,128,1><<<dim3(2048/128, MTOT/128), 256, 0, stream>>>(
            hb, DMODEL, wxzL, DMODEL, xcb, szb, 0, DMODEL);
        // fused conv+silu+xp K-split GEMM (writes ub + xpart)
        xp_conv_kernel<<<dim3(XPSPLIT, MTOT/64), 256, 0, stream>>>(
            xcb, cw, cb, wxpL, ub, xpart);
        // fused xpred + dt GEMM (writes dtb + xdbl B/C)
        dt_fused_kernel<<<dim3(DINNER/64, MTOT/64), 256, 0, stream>>>(
            xpart, wdtL, bdt, dtb, xdbl);
        // chunked selective scan (bf16 chunk states)
        scan1_kernel<<<B_*CHUNKS*(DINNER/256), 256, 0, stream>>>(ub, xdbl, dtb, Alog, hfinal, dsum);
        scan2_kernel<<<(B_*DINNER*DSTATE)/256, 256, 0, stream>>>(hfinal, dsum, Alog);
        scan3_kernel<<<B_*CHUNKS*(DINNER/256), 256, 0, stream>>>(szb, ub, xdbl, dtb, Alog, Dp, hfinal, yb);
        // h = y @ Wout^T (K=1024), 64x64 tile, direct bf16 epilogue
        gemm_bf16<64,64,2><<<dim3(DMODEL/64, MTOT/64), 256, 0, stream>>>(
            yb, DINNER, woutL, DINNER, hb, nullptr, DMODEL, DINNER);
    }

    ln_kernel<<<MTOT, 256, 0, stream>>>(hb, ln_g, ln_b, out);
}